// Round 1
// baseline (1224.989 us; speedup 1.0000x reference)
//
#include <hip/hip_runtime.h>

#define B_ 2
#define N_ 65536
#define DIM_ 256
#define H_ 8
#define CH_ 32
#define M_ 64
#define KOUT_ 512          // H_*M_
#define WCOLS 768          // [0,256): W_fx cols, [256,768): folded logit cols
#define TR 64              // rows per tile
#define GB1 256            // k1 grid
#define TPB1 8             // tiles per k1 block (2048 tiles total)

typedef unsigned int uint32;

__device__ __forceinline__ float bfloat_lo(uint32 x){ union{uint32 i;float f;}v; v.i = x<<16; return v.f; }
__device__ __forceinline__ float bfloat_hi(uint32 x){ union{uint32 i;float f;}v; v.i = x & 0xffff0000u; return v.f; }
__device__ __forceinline__ unsigned short f2bf(float f){
  union{float f; uint32 i;} v; v.f = f;
  uint32 x = v.i;
  return (unsigned short)((x + 0x7fffu + ((x>>16)&1u)) >> 16);  // RNE (finite inputs)
}

// ---------------- prep: fold W_x@W_slice (and 1/temp) into Wbig ----------------
__global__ void prep_kernel(const float* __restrict__ Wfx,
                            const float* __restrict__ bfx,
                            const float* __restrict__ Wx,
                            const float* __restrict__ bx,
                            const float* __restrict__ Wslice,
                            const float* __restrict__ bslice,
                            const float* __restrict__ temperature,
                            float* __restrict__ Wbig,
                            float* __restrict__ bbig)
{
  const int k = blockIdx.x;      // 0..255 (K index)
  const int t = threadIdx.x;     // 256 threads
  for (int c = t; c < WCOLS; c += 256) {
    float val;
    if (c < 256) {
      val = Wfx[k*256 + c];
    } else {
      const int h = (c-256)>>6, m = (c-256)&63;
      const float tmp = fminf(fmaxf(temperature[h], 0.1f), 5.0f);
      float acc = 0.f;
      for (int cc = 0; cc < CH_; cc++) acc += Wx[k*256 + h*CH_ + cc]*Wslice[cc*M_ + m];
      val = acc/tmp;
    }
    Wbig[k*WCOLS + c] = val;
  }
  if (k == 0) {
    for (int c = t; c < WCOLS; c += 256) {
      float bv;
      if (c < 256) {
        bv = bfx[c];
      } else {
        const int h = (c-256)>>6, m = (c-256)&63;
        const float tmp = fminf(fmaxf(temperature[h], 0.1f), 5.0f);
        float acc = bslice[m];
        for (int cc = 0; cc < CH_; cc++) acc += bx[h*CH_ + cc]*Wslice[cc*M_ + m];
        bv = acc/tmp;
      }
      bbig[c] = bv;
    }
  }
}

// ---------------- k1: projections + softmax + slice-token partials ----------------
__global__ __launch_bounds__(512, 2) void k1_kernel(
    const float* __restrict__ x,
    const float* __restrict__ Wbig,
    const float* __restrict__ bbig,
    unsigned short* __restrict__ swg,   // [B][N][512] bf16
    float* __restrict__ stp,            // [GB1][8][64][32] partials
    float* __restrict__ normp)          // [GB1][8][64]
{
  __shared__ float xs[TR*256];             // 64 KiB; reused as fx (fp32) after phase B
  __shared__ unsigned short sws[TR*KOUT_]; // 64 KiB bf16
  const int t  = threadIdx.x;
  const int ty = t>>6, tx = t&63;          // wave = one ty
  const int blk = blockIdx.x;
  const int b = blk>>7, bib = blk&127;     // blocks 0..127 -> b=0

  float bbA[8], bbB[4];
  #pragma unroll
  for (int j=0;j<8;j++) bbA[j] = bbig[256 + (tx<<3) + j];
  #pragma unroll
  for (int j=0;j<4;j++) bbB[j] = bbig[(tx<<2) + j];

  // slice-token partial ownership: h = ty, g in [g0,g0+4), c in [c0,c0+8)
  const int g0 = (tx & 15) << 2;
  const int c0 = (tx >> 4) << 3;
  float accST[4][8];
  float accN[4] = {0.f,0.f,0.f,0.f};
  #pragma unroll
  for (int g=0;g<4;g++)
    #pragma unroll
    for (int c=0;c<8;c++) accST[g][c]=0.f;

  for (int tile=0; tile<TPB1; tile++) {
    const int trow0 = (bib + (tile<<7)) << 6;   // row within this b
    const float* xrow = x + ((size_t)b*N_ + trow0)*256;
    {
      const float4* src = reinterpret_cast<const float4*>(xrow);
      float4* dst = reinterpret_cast<float4*>(xs);
      #pragma unroll
      for (int i=0;i<8;i++) dst[(i<<9)+t] = src[(i<<9)+t];
    }
    __syncthreads();

    // ---- Phase A: logits GEMM (cols 256 + tx*8 .. +7, rows ty*8..+7) ----
    float accA[8][8];
    #pragma unroll
    for (int i=0;i<8;i++)
      #pragma unroll
      for (int j=0;j<8;j++) accA[i][j]=0.f;
    const float* WpA = Wbig + 256 + (tx<<3);
    for (int k=0;k<256;k+=4) {
      float4 xv[8];
      #pragma unroll
      for (int i=0;i<8;i++) xv[i] = *reinterpret_cast<const float4*>(&xs[(((ty<<3)+i)<<8)+k]);
      #pragma unroll
      for (int kk=0;kk<4;kk++) {
        const float* wrow = WpA + (size_t)(k+kk)*WCOLS;
        const float4 w0 = *reinterpret_cast<const float4*>(wrow);
        const float4 w1 = *reinterpret_cast<const float4*>(wrow+4);
        #pragma unroll
        for (int i=0;i<8;i++) {
          const float xval = (kk==0)?xv[i].x:(kk==1)?xv[i].y:(kk==2)?xv[i].z:xv[i].w;
          accA[i][0] = fmaf(xval, w0.x, accA[i][0]);
          accA[i][1] = fmaf(xval, w0.y, accA[i][1]);
          accA[i][2] = fmaf(xval, w0.z, accA[i][2]);
          accA[i][3] = fmaf(xval, w0.w, accA[i][3]);
          accA[i][4] = fmaf(xval, w1.x, accA[i][4]);
          accA[i][5] = fmaf(xval, w1.y, accA[i][5]);
          accA[i][6] = fmaf(xval, w1.z, accA[i][6]);
          accA[i][7] = fmaf(xval, w1.w, accA[i][7]);
        }
      }
    }

    // ---- softmax over m (8-lane groups share h = tx>>3) ----
    unsigned short* swrow_base = swg + ((size_t)b*N_ + trow0)*KOUT_;
    #pragma unroll
    for (int i=0;i<8;i++) {
      float v[8]; float mx = -3.0e38f;
      #pragma unroll
      for (int j=0;j<8;j++){ v[j] = accA[i][j] + bbA[j]; mx = fmaxf(mx, v[j]); }
      mx = fmaxf(mx, __shfl_xor(mx,1));
      mx = fmaxf(mx, __shfl_xor(mx,2));
      mx = fmaxf(mx, __shfl_xor(mx,4));
      float s = 0.f;
      #pragma unroll
      for (int j=0;j<8;j++){ v[j] = __expf(v[j]-mx); s += v[j]; }
      s += __shfl_xor(s,1); s += __shfl_xor(s,2); s += __shfl_xor(s,4);
      const float inv = 1.0f/s;
      union { unsigned short u[8]; float4 f4; } pk;
      #pragma unroll
      for (int j=0;j<8;j++) pk.u[j] = f2bf(v[j]*inv);
      const int r = (ty<<3)+i;
      *reinterpret_cast<float4*>(&sws[r*KOUT_ + (tx<<3)]) = pk.f4;
      *reinterpret_cast<float4*>(swrow_base + (size_t)r*KOUT_ + (tx<<3)) = pk.f4;
    }

    // ---- Phase B: fx GEMM (cols tx*4..+3) ----
    float accB[8][4];
    #pragma unroll
    for (int i=0;i<8;i++)
      #pragma unroll
      for (int j=0;j<4;j++) accB[i][j]=0.f;
    const float* WpB = Wbig + (tx<<2);
    for (int k=0;k<256;k+=4) {
      float4 xv[8];
      #pragma unroll
      for (int i=0;i<8;i++) xv[i] = *reinterpret_cast<const float4*>(&xs[(((ty<<3)+i)<<8)+k]);
      #pragma unroll
      for (int kk=0;kk<4;kk++) {
        const float4 w0 = *reinterpret_cast<const float4*>(WpB + (size_t)(k+kk)*WCOLS);
        #pragma unroll
        for (int i=0;i<8;i++) {
          const float xval = (kk==0)?xv[i].x:(kk==1)?xv[i].y:(kk==2)?xv[i].z:xv[i].w;
          accB[i][0] = fmaf(xval, w0.x, accB[i][0]);
          accB[i][1] = fmaf(xval, w0.y, accB[i][1]);
          accB[i][2] = fmaf(xval, w0.z, accB[i][2]);
          accB[i][3] = fmaf(xval, w0.w, accB[i][3]);
        }
      }
    }
    __syncthreads();   // all xs reads done; safe to overwrite with fx
    #pragma unroll
    for (int i=0;i<8;i++) {
      const int r = (ty<<3)+i;
      float4 f;
      f.x = accB[i][0]+bbB[0]; f.y = accB[i][1]+bbB[1];
      f.z = accB[i][2]+bbB[2]; f.w = accB[i][3]+bbB[3];
      *reinterpret_cast<float4*>(&xs[(r<<8) + (tx<<2)]) = f;
    }
    __syncthreads();

    // ---- slice-token partial accumulation (h=ty) ----
    for (int r=0;r<TR;r++) {
      const uint2 raw = *reinterpret_cast<const uint2*>(&sws[r*KOUT_ + (ty<<6) + g0]);
      float sv[4];
      sv[0] = bfloat_lo(raw.x); sv[1] = bfloat_hi(raw.x);
      sv[2] = bfloat_lo(raw.y); sv[3] = bfloat_hi(raw.y);
      const float4 fa = *reinterpret_cast<const float4*>(&xs[(r<<8) + (ty<<5) + c0]);
      const float4 fb = *reinterpret_cast<const float4*>(&xs[(r<<8) + (ty<<5) + c0 + 4]);
      #pragma unroll
      for (int g=0;g<4;g++) {
        accN[g] += sv[g];
        accST[g][0] = fmaf(sv[g], fa.x, accST[g][0]);
        accST[g][1] = fmaf(sv[g], fa.y, accST[g][1]);
        accST[g][2] = fmaf(sv[g], fa.z, accST[g][2]);
        accST[g][3] = fmaf(sv[g], fa.w, accST[g][3]);
        accST[g][4] = fmaf(sv[g], fb.x, accST[g][4]);
        accST[g][5] = fmaf(sv[g], fb.y, accST[g][5]);
        accST[g][6] = fmaf(sv[g], fb.z, accST[g][6]);
        accST[g][7] = fmaf(sv[g], fb.w, accST[g][7]);
      }
    }
    __syncthreads();   // before next tile overwrites xs/sws
  }

  #pragma unroll
  for (int g=0; g<4; g++) {
    float* p = stp + ((((size_t)blk*8 + ty)*64) + g0+g)*32 + c0;
    float4 o0, o1;
    o0.x=accST[g][0]; o0.y=accST[g][1]; o0.z=accST[g][2]; o0.w=accST[g][3];
    o1.x=accST[g][4]; o1.y=accST[g][5]; o1.z=accST[g][6]; o1.w=accST[g][7];
    *reinterpret_cast<float4*>(p)   = o0;
    *reinterpret_cast<float4*>(p+4) = o1;
  }
  if ((tx>>4)==0) {
    #pragma unroll
    for (int g=0; g<4; g++) normp[((size_t)blk*8 + ty)*64 + g0+g] = accN[g];
  }
}

// ---------------- k2: reduce partials + tiny attention + fold W_out ----------------
__global__ __launch_bounds__(256) void k2_kernel(
    const float* __restrict__ stp,
    const float* __restrict__ normp,
    const float* __restrict__ Wq,
    const float* __restrict__ Wk,
    const float* __restrict__ Wv,
    const float* __restrict__ Wout,
    float* __restrict__ OS2)             // [B][512][256]
{
  __shared__ float tok[64*32];
  __shared__ float nrm[64];
  __shared__ float qL[64*32];
  __shared__ float kL[64*32];
  __shared__ float vL[64*32];
  __shared__ float sc[64*64];
  const int bh = blockIdx.x; const int b = bh>>3, h = bh&7;
  const int t = threadIdx.x;
  const int g = t>>2, q4 = t&3;

  float acc[8] = {0,0,0,0,0,0,0,0}; float an = 0.f;
  for (int gb=0; gb<128; gb++) {
    const float* p = stp + ((((size_t)(b*128+gb)*8 + h)*64) + g)*32 + (q4<<3);
    const float4 v0 = *reinterpret_cast<const float4*>(p);
    const float4 v1 = *reinterpret_cast<const float4*>(p+4);
    acc[0]+=v0.x; acc[1]+=v0.y; acc[2]+=v0.z; acc[3]+=v0.w;
    acc[4]+=v1.x; acc[5]+=v1.y; acc[6]+=v1.z; acc[7]+=v1.w;
    if (q4==0) an += normp[((size_t)(b*128+gb)*8 + h)*64 + g];
  }
  if (q4==0) nrm[g] = an;
  __syncthreads();
  const float inv = 1.0f/(nrm[g] + 1e-5f);
  #pragma unroll
  for (int j=0;j<8;j++) tok[(g<<5) + (q4<<3) + j] = acc[j]*inv;
  __syncthreads();

  // q,k,v
  float aq[8]={0,0,0,0,0,0,0,0}, ak2[8]={0,0,0,0,0,0,0,0}, av[8]={0,0,0,0,0,0,0,0};
  for (int kk=0; kk<32; kk++) {
    const float tv = tok[(g<<5)+kk];
    const int wo = kk*32 + (q4<<3);
    #pragma unroll
    for (int j=0;j<8;j++) {
      aq[j]  = fmaf(tv, Wq[wo+j], aq[j]);
      ak2[j] = fmaf(tv, Wk[wo+j], ak2[j]);
      av[j]  = fmaf(tv, Wv[wo+j], av[j]);
    }
  }
  #pragma unroll
  for (int j=0;j<8;j++){
    qL[(g<<5)+(q4<<3)+j]=aq[j];
    kL[(g<<5)+(q4<<3)+j]=ak2[j];
    vL[(g<<5)+(q4<<3)+j]=av[j];
  }
  __syncthreads();

  // scores row g, this thread: m = q4*16..+15 ; softmax across 4 lanes
  const float scale = 0.17677669529663689f;   // 32^-0.5
  float svv[16]; float mx = -3.0e38f;
  for (int mm=0;mm<16;mm++) {
    const int m = (q4<<4)+mm;
    float s2 = 0.f;
    #pragma unroll
    for (int c=0;c<32;c++) s2 = fmaf(qL[(g<<5)+c], kL[(m<<5)+c], s2);
    s2 *= scale;
    svv[mm] = s2; mx = fmaxf(mx, s2);
  }
  mx = fmaxf(mx, __shfl_xor(mx,1));
  mx = fmaxf(mx, __shfl_xor(mx,2));
  float ssum = 0.f;
  for (int mm=0;mm<16;mm++){ svv[mm] = __expf(svv[mm]-mx); ssum += svv[mm]; }
  ssum += __shfl_xor(ssum,1); ssum += __shfl_xor(ssum,2);
  const float isum = 1.0f/ssum;
  for (int mm=0;mm<16;mm++) sc[(g<<6) + (q4<<4) + mm] = svv[mm]*isum;
  __syncthreads();

  // out_slice = attn @ v
  float os[8]={0,0,0,0,0,0,0,0};
  for (int m=0;m<64;m++) {
    const float a = sc[(g<<6)+m];
    const int vo = (m<<5)+(q4<<3);
    #pragma unroll
    for (int j=0;j<8;j++) os[j] = fmaf(a, vL[vo+j], os[j]);
  }
  __syncthreads();
  #pragma unroll
  for (int j=0;j<8;j++) tok[(g<<5)+(q4<<3)+j] = os[j];   // reuse tok for out_slice
  __syncthreads();

  // OS2[b][h*64+g][d], d = q4*64..+63
  float accO[64];
  #pragma unroll
  for (int d=0;d<64;d++) accO[d]=0.f;
  for (int c=0;c<32;c++) {
    const float tv = tok[(g<<5)+c];
    const float* wrow = Wout + (size_t)(h*32+c)*256 + (q4<<6);
    #pragma unroll
    for (int d=0;d<64;d++) accO[d] = fmaf(tv, wrow[d], accO[d]);
  }
  float* orow = OS2 + ((size_t)b*KOUT_ + h*64 + g)*256 + (q4<<6);
  #pragma unroll
  for (int d=0;d<64;d++) orow[d] = accO[d];
}

// ---------------- k3: out = sw @ OS2 + b_out ----------------
__global__ __launch_bounds__(256, 2) void k3_kernel(
    const unsigned short* __restrict__ swg,
    const float* __restrict__ OS2,
    const float* __restrict__ bout,
    float* __restrict__ out)
{
  __shared__ unsigned short sws[TR*KOUT_];   // 64 KiB
  const int t = threadIdx.x;
  const int blkid = blockIdx.x;              // 0..2047
  const int b = blkid>>10; const int row0 = (blkid&1023)<<6;
  {
    const float4* src = reinterpret_cast<const float4*>(swg + ((size_t)b*N_ + row0)*KOUT_);
    float4* dst = reinterpret_cast<float4*>(sws);
    #pragma unroll
    for (int i=0;i<16;i++) dst[(i<<8)+t] = src[(i<<8)+t];
  }
  __syncthreads();
  const int ty = t>>5, tx = t&31;
  float acc[8][8];
  float bo[8];
  #pragma unroll
  for (int j=0;j<8;j++) bo[j] = bout[(tx<<3)+j];
  #pragma unroll
  for (int i=0;i<8;i++)
    #pragma unroll
    for (int j=0;j<8;j++) acc[i][j]=bo[j];
  const float* Wp = OS2 + (size_t)b*KOUT_*256 + (tx<<3);
  for (int k=0;k<KOUT_;k+=4) {
    float swv[8][4];
    #pragma unroll
    for (int i=0;i<8;i++) {
      const uint2 raw = *reinterpret_cast<const uint2*>(&sws[(((ty<<3)+i)*KOUT_) + k]);
      swv[i][0] = bfloat_lo(raw.x); swv[i][1] = bfloat_hi(raw.x);
      swv[i][2] = bfloat_lo(raw.y); swv[i][3] = bfloat_hi(raw.y);
    }
    #pragma unroll
    for (int kk=0;kk<4;kk++) {
      const float* wrow = Wp + (size_t)(k+kk)*256;
      const float4 w0 = *reinterpret_cast<const float4*>(wrow);
      const float4 w1 = *reinterpret_cast<const float4*>(wrow+4);
      #pragma unroll
      for (int i=0;i<8;i++) {
        const float xval = swv[i][kk];
        acc[i][0]=fmaf(xval,w0.x,acc[i][0]);
        acc[i][1]=fmaf(xval,w0.y,acc[i][1]);
        acc[i][2]=fmaf(xval,w0.z,acc[i][2]);
        acc[i][3]=fmaf(xval,w0.w,acc[i][3]);
        acc[i][4]=fmaf(xval,w1.x,acc[i][4]);
        acc[i][5]=fmaf(xval,w1.y,acc[i][5]);
        acc[i][6]=fmaf(xval,w1.z,acc[i][6]);
        acc[i][7]=fmaf(xval,w1.w,acc[i][7]);
      }
    }
  }
  #pragma unroll
  for (int i=0;i<8;i++) {
    const int r = row0 + (ty<<3) + i;
    float* orow = out + ((size_t)b*N_ + r)*256 + (tx<<3);
    float4 o0; o0.x=acc[i][0]; o0.y=acc[i][1]; o0.z=acc[i][2]; o0.w=acc[i][3];
    float4 o1; o1.x=acc[i][4]; o1.y=acc[i][5]; o1.z=acc[i][6]; o1.w=acc[i][7];
    *reinterpret_cast<float4*>(orow)   = o0;
    *reinterpret_cast<float4*>(orow+4) = o1;
  }
}

extern "C" void kernel_launch(void* const* d_in, const int* in_sizes, int n_in,
                              void* d_out, int out_size, void* d_ws, size_t ws_size,
                              hipStream_t stream)
{
  const float* x     = (const float*)d_in[0];
  const float* Wfx   = (const float*)d_in[1];
  const float* bfx   = (const float*)d_in[2];
  const float* Wx    = (const float*)d_in[3];
  const float* bx    = (const float*)d_in[4];
  const float* Wsl   = (const float*)d_in[5];
  const float* bsl   = (const float*)d_in[6];
  const float* temp  = (const float*)d_in[7];
  const float* Wq    = (const float*)d_in[8];
  const float* Wk    = (const float*)d_in[9];
  const float* Wv    = (const float*)d_in[10];
  const float* Wout  = (const float*)d_in[11];
  const float* bout  = (const float*)d_in[12];
  float* out = (float*)d_out;

  char* ws = (char*)d_ws;
  // ws layout (bytes):
  //   Wbig  [256][768] f32 : 0       .. 786432
  //   bbig  [768]      f32 : 786432  .. 789504
  //   swg   [2][65536][512] bf16 : 789504 .. 135007232
  //   stp   [256][8][64][32] f32 : 135007232 .. 151784448
  //   normp [256][8][64]     f32 : 151784448 .. 152308736
  //   OS2   [2][512][256]    f32 : 152308736 .. 153357312  (~146.3 MB total)
  float* Wbig  = (float*)(ws);
  float* bbig  = (float*)(ws + 786432);
  unsigned short* swg = (unsigned short*)(ws + 789504);
  float* stp   = (float*)(ws + 135007232);
  float* normp = (float*)(ws + 151784448);
  float* OS2   = (float*)(ws + 152308736);

  prep_kernel<<<dim3(256), dim3(256), 0, stream>>>(Wfx,bfx,Wx,bx,Wsl,bsl,temp,Wbig,bbig);
  k1_kernel<<<dim3(GB1), dim3(512), 0, stream>>>(x, Wbig, bbig, swg, stp, normp);
  k2_kernel<<<dim3(16), dim3(256), 0, stream>>>(stp, normp, Wq, Wk, Wv, Wout, OS2);
  k3_kernel<<<dim3(2048), dim3(256), 0, stream>>>(swg, OS2, bout, out);
}

// Round 3
// 506.350 us; speedup vs baseline: 2.4193x; 2.4193x over previous
//
#include <hip/hip_runtime.h>

#define N_ 65536

typedef unsigned int  uint32;
typedef unsigned short ushort;
typedef float  f32x4 __attribute__((ext_vector_type(4)));
typedef short  s16x8 __attribute__((ext_vector_type(8)));
typedef uint32 u32x2 __attribute__((ext_vector_type(2)));

__device__ __forceinline__ uint32 f2bf(float f){
  union{float f; uint32 i;} v; v.f=f;
  return (v.i + 0x7fffu + ((v.i>>16)&1u)) >> 16;   // RNE
}
__device__ __forceinline__ float bfl(uint32 h){     // bf16 (low 16 bits) -> float
  union{uint32 i; float f;} v; v.i = h<<16; return v.f;
}
__device__ __forceinline__ uint32 pk2(float a, float b){
  return f2bf(a) | (f2bf(b)<<16);
}
__device__ __forceinline__ f32x4 mfma16(s16x8 a, s16x8 b, f32x4 c){
  return __builtin_amdgcn_mfma_f32_16x16x32_bf16(a,b,c,0,0,0);
}

// ---------------- prep: WlT[512][256], WfxT[256][256] (bf16, k-inner), blT[512] ----------------
__global__ __launch_bounds__(256) void prep_kernel(
    const float* __restrict__ Wfx, const float* __restrict__ Wx,
    const float* __restrict__ Wsl, const float* __restrict__ bsl,
    const float* __restrict__ bx,  const float* __restrict__ temp,
    ushort* __restrict__ WlT, ushort* __restrict__ WfxT, float* __restrict__ blT)
{
  const int blk = blockIdx.x, t = threadIdx.x;
  if (blk < 512){
    const int m = blk, h = m>>6, mp = m&63;
    const float tmp = fminf(fmaxf(temp[h],0.1f),5.0f);
    float s = 0.f;
    #pragma unroll
    for (int cc=0; cc<32; cc++) s += Wx[t*256 + h*32+cc]*Wsl[cc*64+mp];
    WlT[m*256+t] = (ushort)f2bf(s/tmp);
    if (t==0){
      float bs = bsl[mp];
      for (int cc=0; cc<32; cc++) bs += bx[h*32+cc]*Wsl[cc*64+mp];
      blT[m] = bs/tmp;
    }
  } else {
    const int c = blk-512;
    WfxT[c*256+t] = (ushort)f2bf(Wfx[t*256+c]);
  }
}

// ---------------- k1a: fused proj + softmax + slice-token partials ----------------
// wave w owns head w.  LDS: X tile [128][256] bf16 swizzled at [0,64K);
// after Phase B (barrier), per-wave C-regions at w*16K: swL [64 m][128B] (8K),
// fxLh [32 c][128B] (4K), fxLl (4K).
__global__ __launch_bounds__(512) void k1a_kernel(
    const float* __restrict__ x,
    const ushort* __restrict__ WlT,
    const ushort* __restrict__ WfxT,
    const float* __restrict__ blT,
    const float* __restrict__ bfx,
    ushort* __restrict__ swg,       // [B*N][512] bf16 (m-inner)
    float* __restrict__ stp,        // [256][8][32][64] f32
    float* __restrict__ normp)      // [256][8][64]
{
  __shared__ __align__(16) char smem[131072];
  const int t = threadIdx.x;
  const int w = t>>6, l = t&63, rg = l>>4, c16 = l&15;
  const int blk = blockIdx.x;
  const int bidx = blk>>7;
  const int tile0 = ((blk&127)<<2) + (bidx<<9);

  char* cb = smem + (w<<14);   // per-wave 16KB C-region

  f32x4 pc[2][4];      // Phase C accumulators: [c-block][m-block], D row=channel, col=m
  #pragma unroll
  for (int i=0;i<2;i++)
    #pragma unroll
    for (int j=0;j<4;j++) pc[i][j] = (f32x4){0.f,0.f,0.f,0.f};
  f32x4 nacc[4];
  #pragma unroll
  for (int i=0;i<4;i++) nacc[i] = (f32x4){0.f,0.f,0.f,0.f};

  f32x4 blv[4];
  #pragma unroll
  for (int m=0;m<4;m++) blv[m] = *(const f32x4*)(blT + (w<<6)+(m<<4)+(rg<<2));
  float bfv[2];
  #pragma unroll
  for (int c=0;c<2;c++) bfv[c] = bfx[(w<<5)+(c<<4)+c16];

  for (int it=0; it<4; ++it) {
    const int tile = tile0 + it;
    const long gn0 = (long)tile<<7;

    __syncthreads();   // everyone done with smem (X / C-regions of prev tile)
    // ---- stage X tile [128][256] -> bf16 LDS, XOR-swizzled ----
    {
      const float4* xs = (const float4*)(x + (gn0<<8));
      #pragma unroll
      for (int p=0;p<16;p++){
        const int f = t + (p<<9);
        const int row = f>>6, q = f&63;
        const float4 v = xs[f];
        u32x2 uu; uu.x = pk2(v.x, v.y); uu.y = pk2(v.z, v.w);
        *(u32x2*)(smem + (row<<9) + ((q<<3) ^ ((row&7)<<4))) = uu;
      }
    }
    __syncthreads();

    // ---- Phase A (logits^T = WlT @ X^T): D rows = m (regs), cols = points (lanes) ----
    u32x2 pk[4][8];    // softmax'd sw bf16, per (m-block, pt-block): 4 m-vals at pt col c16
    #pragma unroll
    for (int nh=0; nh<2; nh++){
      f32x4 accA[4][4];
      #pragma unroll
      for (int m=0;m<4;m++)
        #pragma unroll
        for (int n=0;n<4;n++) accA[m][n] = (f32x4){0.f,0.f,0.f,0.f};
      #pragma unroll
      for (int kb=0;kb<8;kb++){
        s16x8 aW[4], bX[4];
        #pragma unroll
        for (int m=0;m<4;m++)
          aW[m] = *(const s16x8*)(WlT + (((w<<6)+(m<<4)+c16)<<8) + (kb<<5)+(rg<<3));
        #pragma unroll
        for (int n=0;n<4;n++){
          const int row = (((nh<<2)+n)<<4) | c16;
          bX[n] = *(const s16x8*)(smem + (row<<9) + (((kb<<6)+(rg<<4)) ^ ((row&7)<<4)));
        }
        #pragma unroll
        for (int m=0;m<4;m++)
          #pragma unroll
          for (int n=0;n<4;n++)
            accA[m][n] = mfma16(aW[m], bX[n], accA[m][n]);
      }
      // softmax over m (64 vals: 4 m-blocks in-reg x 4 rg-groups cross-lane)
      #pragma unroll
      for (int n=0;n<4;n++){
        f32x4 v[4];
        float mx = -3.0e38f;
        #pragma unroll
        for (int m=0;m<4;m++){
          v[m] = accA[m][n] + blv[m];
          mx = fmaxf(mx, fmaxf(fmaxf(v[m].x, v[m].y), fmaxf(v[m].z, v[m].w)));
        }
        mx = fmaxf(mx, __shfl_xor(mx,16));
        mx = fmaxf(mx, __shfl_xor(mx,32));
        float s = 0.f;
        #pragma unroll
        for (int m=0;m<4;m++){
          v[m].x = __expf(v[m].x-mx); v[m].y = __expf(v[m].y-mx);
          v[m].z = __expf(v[m].z-mx); v[m].w = __expf(v[m].w-mx);
          s += v[m].x+v[m].y+v[m].z+v[m].w;
        }
        s += __shfl_xor(s,16);
        s += __shfl_xor(s,32);
        const float inv = 1.0f/s;
        const long gn = gn0 + (((nh<<2)+n)<<4) + c16;
        #pragma unroll
        for (int m=0;m<4;m++){
          f32x4 sv = v[m]*inv;
          nacc[m] += sv;
          u32x2 p; p.x = pk2(sv.x, sv.y); p.y = pk2(sv.z, sv.w);
          pk[m][(nh<<2)+n] = p;
          *(u32x2*)(swg + (gn<<9) + (w<<6)+(m<<4)+(rg<<2)) = p;
        }
      }
    }

    // ---- Phase B (fx = X @ Wfx): D rows = points (regs), cols = channels (lanes) ----
    u32x2 qkh[2][8], qkl[2][8];   // fx hi/lo bf16 per (c-block, pt-block)
    #pragma unroll
    for (int rh=0; rh<2; rh++){
      f32x4 accB[4][2];
      #pragma unroll
      for (int r=0;r<4;r++)
        #pragma unroll
        for (int c=0;c<2;c++) accB[r][c] = (f32x4){0.f,0.f,0.f,0.f};
      #pragma unroll
      for (int kb=0;kb<8;kb++){
        s16x8 bW[2], aX[4];
        #pragma unroll
        for (int c=0;c<2;c++)
          bW[c] = *(const s16x8*)(WfxT + (((w<<5)+(c<<4)+c16)<<8) + (kb<<5)+(rg<<3));
        #pragma unroll
        for (int r=0;r<4;r++){
          const int row = (((rh<<2)+r)<<4) | c16;
          aX[r] = *(const s16x8*)(smem + (row<<9) + (((kb<<6)+(rg<<4)) ^ ((row&7)<<4)));
        }
        #pragma unroll
        for (int r=0;r<4;r++)
          #pragma unroll
          for (int c=0;c<2;c++)
            accB[r][c] = mfma16(aX[r], bW[c], accB[r][c]);
      }
      #pragma unroll
      for (int r=0;r<4;r++)
        #pragma unroll
        for (int c=0;c<2;c++){
          const float v0 = accB[r][c].x+bfv[c], v1 = accB[r][c].y+bfv[c];
          const float v2 = accB[r][c].z+bfv[c], v3 = accB[r][c].w+bfv[c];
          const uint32 h0=f2bf(v0), h1=f2bf(v1), h2=f2bf(v2), h3=f2bf(v3);
          u32x2 ph; ph.x = h0|(h1<<16); ph.y = h2|(h3<<16);
          qkh[c][(rh<<2)+r] = ph;
          u32x2 pl;
          pl.x = f2bf(v0-bfl(h0)) | (f2bf(v1-bfl(h1))<<16);
          pl.y = f2bf(v2-bfl(h2)) | (f2bf(v3-bfl(h3))<<16);
          qkl[c][(rh<<2)+r] = pl;
        }
    }
    __syncthreads();   // all X reads done; C-regions may overlay X

    // ---- Phase C: per nh-half (64 points): stage fx/sw to LDS, then MFMA ----
    #pragma unroll
    for (int nh=0; nh<2; nh++){
      // fx: D-frag regs are point-contiguous -> direct 8B stores into [c][pt]
      #pragma unroll
      for (int cf=0; cf<2; cf++)
        #pragma unroll
        for (int nb=0; nb<4; nb++){
          const int row = (cf<<4) + c16;
          const int cby = ((nb<<5) + (rg<<3)) ^ ((row&7)<<4);
          *(u32x2*)(cb + 8192  + (row<<7) + cby) = qkh[cf][(nh<<2)+nb];
          *(u32x2*)(cb + 12288 + (row<<7) + cby) = qkl[cf][(nh<<2)+nb];
        }
      // sw: pair-pack transpose (regs=m) -> [m][pt]
      #pragma unroll
      for (int mb=0; mb<4; mb++)
        #pragma unroll
        for (int nb=0; nb<4; nb++){
          u32x2 d = pk[mb][(nh<<2)+nb];
          const uint32 px = (uint32)__shfl_xor((int)d.x, 1);
          const uint32 py = (uint32)__shfl_xor((int)d.y, 1);
          const bool ev = ((c16&1)==0);
          const uint32 s0 = ev ? (uint32)d.x : py;
          const uint32 s1 = ev ? px : (uint32)d.y;
          const uint32 wA = (s0 & 0xffffu) | (s1<<16);
          const uint32 wB = (s0>>16) | (s1 & 0xffff0000u);
          const int rowA = (mb<<4) + (rg<<2) + (ev?0:2);
          const int cbyt = ((nb<<4) + (c16 & ~1)) << 1;
          *(uint32*)(cb + ((rowA  )<<7) + (cbyt ^ (((rowA  )&7)<<4))) = wA;
          *(uint32*)(cb + ((rowA+1)<<7) + (cbyt ^ (((rowA+1)&7)<<4))) = wB;
        }
      __syncthreads();   // ordering fence (stores -> loads), also cross-type safe
      #pragma unroll
      for (int kb2=0; kb2<2; kb2++){
        const int pby = (kb2<<6) + (rg<<4);
        s16x8 afh[2], afl[2], bfr[4];
        #pragma unroll
        for (int cf=0; cf<2; cf++){
          const int row = (cf<<4)+c16;
          const int o = pby ^ ((row&7)<<4);
          afh[cf] = *(const s16x8*)(cb + 8192  + (row<<7) + o);
          afl[cf] = *(const s16x8*)(cb + 12288 + (row<<7) + o);
        }
        #pragma unroll
        for (int mf=0; mf<4; mf++){
          const int row = (mf<<4)+c16;
          bfr[mf] = *(const s16x8*)(cb + (row<<7) + (pby ^ ((row&7)<<4)));
        }
        #pragma unroll
        for (int cf=0; cf<2; cf++)
          #pragma unroll
          for (int mf=0; mf<4; mf++){
            pc[cf][mf] = mfma16(afh[cf], bfr[mf], pc[cf][mf]);
            pc[cf][mf] = mfma16(afl[cf], bfr[mf], pc[cf][mf]);
          }
      }
      __syncthreads();   // reads done before next-half staging overwrites
    }
  } // tiles

  // ---- epilogue: norm reduce + stores ----
  #pragma unroll
  for (int m=0;m<4;m++){
    #pragma unroll
    for (int d=1; d<16; d<<=1){
      nacc[m].x += __shfl_xor(nacc[m].x, d);
      nacc[m].y += __shfl_xor(nacc[m].y, d);
      nacc[m].z += __shfl_xor(nacc[m].z, d);
      nacc[m].w += __shfl_xor(nacc[m].w, d);
    }
  }
  if (c16==0){
    #pragma unroll
    for (int m=0;m<4;m++)
      *(f32x4*)(normp + (((blk<<3)+w)<<6) + (m<<4) + (rg<<2)) = nacc[m];
  }
  const long sb = ((long)((blk<<3)+w))<<11;   // stp[blk][w][32 c][64 m]
  #pragma unroll
  for (int cf=0;cf<2;cf++)
    #pragma unroll
    for (int mf=0;mf<4;mf++)
      #pragma unroll
      for (int r=0;r<4;r++){
        const int cc = (cf<<4)+(rg<<2)+r;
        stp[sb + (cc<<6) + (mf<<4) + c16] = pc[cf][mf][r];
      }
}

// ---------------- k2a: hierarchical partial reduce (in-place into chunk-slot grp*16) ----------------
__global__ __launch_bounds__(256) void k2a_kernel(float* __restrict__ stp, float* __restrict__ normp)
{
  const int gid = blockIdx.x;           // 128 = 16 bh * 8 grp
  const int bh = gid>>3, grp = gid&7;
  const int b = bh>>3, h = bh&7;
  const int t = threadIdx.x;
  const int blk0 = (b<<7) + (grp<<4);
  f32x4 a0 = {0,0,0,0}, a1 = {0,0,0,0};
  for (int i=0;i<16;i++){
    const f32x4* p = (const f32x4*)(stp + ((((size_t)(blk0+i)<<3)+h)<<11) + ((size_t)t<<3));
    a0 += p[0]; a1 += p[1];
  }
  f32x4* q = (f32x4*)(stp + ((((size_t)blk0<<3)+h)<<11) + ((size_t)t<<3));
  q[0] = a0; q[1] = a1;
  if (t<8){
    f32x4 n0 = {0,0,0,0}, n1 = {0,0,0,0};
    for (int i=0;i<16;i++){
      const f32x4* p = (const f32x4*)(normp + (((blk0+i)<<3)+h)*64 + (t<<3));
      n0 += p[0]; n1 += p[1];
    }
    f32x4* qn = (f32x4*)(normp + ((blk0<<3)+h)*64 + (t<<3));
    qn[0] = n0; qn[1] = n1;
  }
}

// ---------------- k2b: final reduce + tiny attention + fold W_out -> OS2T hi/lo bf16 ----------------
__global__ __launch_bounds__(256) void k2b_kernel(
    const float* __restrict__ stp, const float* __restrict__ normp,
    const float* __restrict__ Wq, const float* __restrict__ Wk, const float* __restrict__ Wv,
    const float* __restrict__ Wout, ushort* __restrict__ OS2Th, ushort* __restrict__ OS2Tl)
{
  __shared__ float nrmL[64];
  __shared__ float tok[2048];
  __shared__ float qL[2048], kL[2048], vL[2048];
  __shared__ float sc[4096];
  __shared__ float osL[2048];
  const int bh = blockIdx.x; const int b = bh>>3, h = bh&7;
  const int t = threadIdx.x;

  if (t<64){
    float s = 0.f;
    for (int g=0; g<8; g++) s += normp[((((b<<7)+(g<<4))<<3)+h)*64 + t];
    nrmL[t] = s;
  }
  __syncthreads();
  {
    f32x4 a0 = {0,0,0,0}, a1 = {0,0,0,0};
    for (int g=0; g<8; g++){
      const f32x4* p = (const f32x4*)(stp + ((((size_t)((b<<7)+(g<<4))<<3)+h)<<11) + ((size_t)t<<3));
      a0 += p[0]; a1 += p[1];
    }
    const int c = t>>3, m0 = (t&7)<<3;
    #pragma unroll
    for (int j=0;j<4;j++) tok[(m0+j)*32 + c]   = a0[j] / (nrmL[m0+j]   + 1e-5f);
    #pragma unroll
    for (int j=0;j<4;j++) tok[(m0+4+j)*32 + c] = a1[j] / (nrmL[m0+4+j] + 1e-5f);
  }
  __syncthreads();

  const int g = t>>2, q4 = t&3;
  float aq[8]={0,0,0,0,0,0,0,0}, ak2[8]={0,0,0,0,0,0,0,0}, av[8]={0,0,0,0,0,0,0,0};
  for (int kk=0; kk<32; kk++){
    const float tv = tok[(g<<5)+kk];
    const int wo = kk*32 + (q4<<3);
    #pragma unroll
    for (int j=0;j<8;j++){
      aq[j]  = fmaf(tv, Wq[wo+j], aq[j]);
      ak2[j] = fmaf(tv, Wk[wo+j], ak2[j]);
      av[j]  = fmaf(tv, Wv[wo+j], av[j]);
    }
  }
  #pragma unroll
  for (int j=0;j<8;j++){
    qL[(g<<5)+(q4<<3)+j]=aq[j];
    kL[(g<<5)+(q4<<3)+j]=ak2[j];
    vL[(g<<5)+(q4<<3)+j]=av[j];
  }
  __syncthreads();

  const float scale = 0.17677669529663689f;
  float svv[16]; float mx = -3.0e38f;
  for (int mm=0;mm<16;mm++){
    const int m = (q4<<4)+mm;
    float s2 = 0.f;
    #pragma unroll
    for (int c=0;c<32;c++) s2 = fmaf(qL[(g<<5)+c], kL[(m<<5)+c], s2);
    s2 *= scale;
    svv[mm] = s2; mx = fmaxf(mx, s2);
  }
  mx = fmaxf(mx, __shfl_xor(mx,1));
  mx = fmaxf(mx, __shfl_xor(mx,2));
  float ssum = 0.f;
  for (int mm=0;mm<16;mm++){ svv[mm] = __expf(svv[mm]-mx); ssum += svv[mm]; }
  ssum += __shfl_xor(ssum,1); ssum += __shfl_xor(ssum,2);
  const float isum = 1.0f/ssum;
  for (int mm=0;mm<16;mm++) sc[(g<<6) + (q4<<4) + mm] = svv[mm]*isum;
  __syncthreads();

  float os[8]={0,0,0,0,0,0,0,0};
  for (int m=0;m<64;m++){
    const float a = sc[(g<<6)+m];
    const int vo = (m<<5)+(q4<<3);
    #pragma unroll
    for (int j=0;j<8;j++) os[j] = fmaf(a, vL[vo+j], os[j]);
  }
  #pragma unroll
  for (int j=0;j<8;j++) osL[(g<<5)+(q4<<3)+j] = os[j];
  __syncthreads();

  // OS2T{h,l}[b][d][h*64+g] = sum_c os[g][c] * Wout[h*32+c][d]  (split bf16)
  const int d = t;
  float wcol[32];
  #pragma unroll
  for (int c=0;c<32;c++) wcol[c] = Wout[(h*32+c)*256 + d];
  uint32* orh = (uint32*)(OS2Th + ((size_t)(b*256+d))*512 + h*64);
  uint32* orl = (uint32*)(OS2Tl + ((size_t)(b*256+d))*512 + h*64);
  #pragma unroll 4
  for (int g2=0; g2<32; g2++){
    float s0=0.f, s1=0.f;
    #pragma unroll
    for (int c=0;c<32;c++){
      s0 = fmaf(osL[((g2*2  )<<5)+c], wcol[c], s0);
      s1 = fmaf(osL[((g2*2+1)<<5)+c], wcol[c], s1);
    }
    const uint32 h0 = f2bf(s0), h1 = f2bf(s1);
    orh[g2] = h0 | (h1<<16);
    orl[g2] = f2bf(s0 - bfl(h0)) | (f2bf(s1 - bfl(h1)) << 16);
  }
}

// ---------------- k3: out = swg @ (OS2Th+OS2Tl)^T + b_out (register MFMA GEMM) ----------------
__global__ __launch_bounds__(256) void k3_kernel(
    const ushort* __restrict__ swg,
    const ushort* __restrict__ OS2Th,
    const ushort* __restrict__ OS2Tl,
    const float* __restrict__ bout,
    float* __restrict__ out)
{
  const int t = threadIdx.x, w = t>>6, l = t&63, rg = l>>4, c16 = l&15;
  const int blk = blockIdx.x;
  const long gn0 = (long)blk<<7;
  const int b = blk>>9;
  f32x4 acc[8][4];
  #pragma unroll
  for (int r=0;r<8;r++)
    #pragma unroll
    for (int c=0;c<4;c++) acc[r][c] = (f32x4){0.f,0.f,0.f,0.f};
  const ushort* swp = swg + (gn0<<9);
  const long obb = (((long)(b<<8) + (w<<6))<<9);
  for (int kb=0;kb<16;kb++){
    s16x8 aS[8];
    #pragma unroll
    for (int r=0;r<8;r++)
      aS[r] = *(const s16x8*)(swp + ((long)((r<<4)+c16)<<9) + (kb<<5)+(rg<<3));
    #pragma unroll
    for (int c=0;c<4;c++){
      const long ro = obb + ((long)((c<<4)+c16)<<9) + (kb<<5)+(rg<<3);
      const s16x8 bh = *(const s16x8*)(OS2Th + ro);
      const s16x8 bl = *(const s16x8*)(OS2Tl + ro);
      #pragma unroll
      for (int r=0;r<8;r++)
        acc[r][c] = mfma16(aS[r], bh, acc[r][c]);
      #pragma unroll
      for (int r=0;r<8;r++)
        acc[r][c] = mfma16(aS[r], bl, acc[r][c]);
    }
  }
  float bo[4];
  #pragma unroll
  for (int c=0;c<4;c++) bo[c] = bout[(w<<6)+(c<<4)+c16];
  #pragma unroll
  for (int r=0;r<8;r++)
    #pragma unroll
    for (int c=0;c<4;c++)
      #pragma unroll
      for (int rr=0;rr<4;rr++)
        out[((gn0 + (r<<4)+(rg<<2)+rr)<<8) + (w<<6)+(c<<4)+c16] = acc[r][c][rr] + bo[c];
}

extern "C" void kernel_launch(void* const* d_in, const int* in_sizes, int n_in,
                              void* d_out, int out_size, void* d_ws, size_t ws_size,
                              hipStream_t stream)
{
  const float* x     = (const float*)d_in[0];
  const float* Wfx   = (const float*)d_in[1];
  const float* bfx   = (const float*)d_in[2];
  const float* Wx    = (const float*)d_in[3];
  const float* bx    = (const float*)d_in[4];
  const float* Wsl   = (const float*)d_in[5];
  const float* bsl   = (const float*)d_in[6];
  const float* temp  = (const float*)d_in[7];
  const float* Wq    = (const float*)d_in[8];
  const float* Wk    = (const float*)d_in[9];
  const float* Wv    = (const float*)d_in[10];
  const float* Wout  = (const float*)d_in[11];
  const float* bout  = (const float*)d_in[12];
  float* out = (float*)d_out;

  char* ws = (char*)d_ws;
  // ws layout (bytes), total 152,963,072:
  ushort* WlT   = (ushort*)(ws);                   // 262144
  ushort* WfxT  = (ushort*)(ws + 262144);          // 131072
  float*  blT   = (float*) (ws + 393216);          // 2048
  ushort* swg   = (ushort*)(ws + 395264);          // 134217728
  float*  stp   = (float*) (ws + 134612992);       // 16777216
  float*  normp = (float*) (ws + 151390208);       // 524288
  ushort* OS2Th = (ushort*)(ws + 151914496);       // 524288
  ushort* OS2Tl = (ushort*)(ws + 152438784);       // 524288

  prep_kernel<<<dim3(768), dim3(256), 0, stream>>>(Wfx, Wx, Wsl, bsl, bx, temp, WlT, WfxT, blT);
  k1a_kernel<<<dim3(256), dim3(512), 0, stream>>>(x, WlT, WfxT, blT, bfx, swg, stp, normp);
  k2a_kernel<<<dim3(128), dim3(256), 0, stream>>>(stp, normp);
  k2b_kernel<<<dim3(16), dim3(256), 0, stream>>>(stp, normp, Wq, Wk, Wv, Wout, OS2Th, OS2Tl);
  k3_kernel<<<dim3(1024), dim3(256), 0, stream>>>(swg, OS2Th, OS2Tl, bout, out);
}

// Round 4
// 497.135 us; speedup vs baseline: 2.4641x; 1.0185x over previous
//
#include <hip/hip_runtime.h>

#define N_ 65536

typedef unsigned int  uint32;
typedef unsigned short ushort;
typedef float  f32x4 __attribute__((ext_vector_type(4)));
typedef short  s16x8 __attribute__((ext_vector_type(8)));
typedef uint32 u32x2 __attribute__((ext_vector_type(2)));

__device__ __forceinline__ uint32 f2bf(float f){
  union{float f; uint32 i;} v; v.f=f;
  return (v.i + 0x7fffu + ((v.i>>16)&1u)) >> 16;   // RNE
}
__device__ __forceinline__ float bfl(uint32 h){     // bf16 (low 16 bits) -> float
  union{uint32 i; float f;} v; v.i = h<<16; return v.f;
}
__device__ __forceinline__ uint32 pk2(float a, float b){
  return f2bf(a) | (f2bf(b)<<16);
}
__device__ __forceinline__ f32x4 mfma16(s16x8 a, s16x8 b, f32x4 c){
  return __builtin_amdgcn_mfma_f32_16x16x32_bf16(a,b,c,0,0,0);
}

// ---------------- prep: WlT[512][256], WfxT[256][256] (bf16, k-inner), blT[512] ----------------
__global__ __launch_bounds__(256) void prep_kernel(
    const float* __restrict__ Wfx, const float* __restrict__ Wx,
    const float* __restrict__ Wsl, const float* __restrict__ bsl,
    const float* __restrict__ bx,  const float* __restrict__ temp,
    ushort* __restrict__ WlT, ushort* __restrict__ WfxT, float* __restrict__ blT)
{
  const int blk = blockIdx.x, t = threadIdx.x;
  if (blk < 512){
    const int m = blk, h = m>>6, mp = m&63;
    const float tmp = fminf(fmaxf(temp[h],0.1f),5.0f);
    float s = 0.f;
    #pragma unroll
    for (int cc=0; cc<32; cc++) s += Wx[t*256 + h*32+cc]*Wsl[cc*64+mp];
    WlT[m*256+t] = (ushort)f2bf(s/tmp);
    if (t==0){
      float bs = bsl[mp];
      for (int cc=0; cc<32; cc++) bs += bx[h*32+cc]*Wsl[cc*64+mp];
      blT[m] = bs/tmp;
    }
  } else {
    const int c = blk-512;
    WfxT[c*256+t] = (ushort)f2bf(Wfx[t*256+c]);
  }
}

// ---------------- k1a: fused proj + softmax + slice-token partials ----------------
// LDS map: [0,64K) X tile [128 rows][512B] (swizzled); after S3 barrier, per-wave
// fx overlay at w*8K (hi 4K [32c][128B] + lo 4K). [64K,128K): per-wave swL at
// 64K+w*8K: [64 m][128B] (swizzled), wave-private (ordered by lgkmcnt only).
__global__ __launch_bounds__(512) __attribute__((amdgpu_waves_per_eu(2,2)))
void k1a_kernel(
    const float* __restrict__ x,
    const ushort* __restrict__ WlT,
    const ushort* __restrict__ WfxT,
    const float* __restrict__ blT,
    const float* __restrict__ bfx,
    ushort* __restrict__ swg,       // [B*N][512] bf16 (m-inner)
    float* __restrict__ stp,        // [256][8][32][64] f32
    float* __restrict__ normp)      // [256][8][64]
{
  __shared__ __align__(16) char smem[131072];
  const int t = threadIdx.x;
  const int w = t>>6, l = t&63, rg = l>>4, c16 = l&15;
  const int blk = blockIdx.x;
  const int bidx = blk>>7;
  const int tile0 = ((blk&127)<<2) + (bidx<<9);

  char* fxh = smem + (w<<13);            // 4 KB per wave (X overlay)
  char* fxl = smem + (w<<13) + 4096;     // 4 KB per wave (X overlay)
  char* swb = smem + 65536 + (w<<13);    // 8 KB per wave

  f32x4 pc[2][4];      // Phase C accumulators: [c-block][m-block]
  #pragma unroll
  for (int i=0;i<2;i++)
    #pragma unroll
    for (int j=0;j<4;j++) pc[i][j] = (f32x4){0.f,0.f,0.f,0.f};
  f32x4 nacc[4];
  #pragma unroll
  for (int i=0;i<4;i++) nacc[i] = (f32x4){0.f,0.f,0.f,0.f};

  f32x4 blv[4];
  #pragma unroll
  for (int m=0;m<4;m++) blv[m] = *(const f32x4*)(blT + (w<<6)+(m<<4)+(rg<<2));
  float bfv[2];
  #pragma unroll
  for (int c=0;c<2;c++) bfv[c] = bfx[(w<<5)+(c<<4)+c16];

  for (int it=0; it<4; ++it) {
    const int tile = tile0 + it;
    const long gn0 = (long)tile<<7;

    __syncthreads();   // S1: prev tile's C reads of fx overlay done -> X region free
    // ---- stage X tile [128][256] -> bf16 LDS, XOR-swizzled ----
    {
      const float4* xs = (const float4*)(x + (gn0<<8));
      #pragma unroll
      for (int p=0;p<16;p++){
        const int f = t + (p<<9);
        const int row = f>>6, q = f&63;
        const float4 v = xs[f];
        u32x2 uu; uu.x = pk2(v.x, v.y); uu.y = pk2(v.z, v.w);
        *(u32x2*)(smem + (row<<9) + ((q<<3) ^ ((row&7)<<4))) = uu;
      }
    }
    __syncthreads();   // S2: X ready

    // ---- Phase A (logits^T = WlT @ X^T) + softmax; h0 staged to swL inline, h1 kept in pk1 ----
    u32x2 pk1[4][4];
    #pragma unroll
    for (int nh=0; nh<2; nh++){
      f32x4 accA[4][4];
      #pragma unroll
      for (int m=0;m<4;m++)
        #pragma unroll
        for (int n=0;n<4;n++) accA[m][n] = (f32x4){0.f,0.f,0.f,0.f};
      #pragma unroll
      for (int kb=0;kb<8;kb++){
        s16x8 aW[4], bX[4];
        #pragma unroll
        for (int m=0;m<4;m++)
          aW[m] = *(const s16x8*)(WlT + (((w<<6)+(m<<4)+c16)<<8) + (kb<<5)+(rg<<3));
        #pragma unroll
        for (int n=0;n<4;n++){
          const int row = (((nh<<2)+n)<<4) | c16;
          bX[n] = *(const s16x8*)(smem + (row<<9) + (((kb<<6)+(rg<<4)) ^ ((row&7)<<4)));
        }
        #pragma unroll
        for (int m=0;m<4;m++)
          #pragma unroll
          for (int n=0;n<4;n++)
            accA[m][n] = mfma16(aW[m], bX[n], accA[m][n]);
      }
      // softmax over m (4 m-blocks in-reg x 4 rg-groups cross-lane)
      #pragma unroll
      for (int n=0;n<4;n++){
        f32x4 v[4];
        float mx = -3.0e38f;
        #pragma unroll
        for (int m=0;m<4;m++){
          v[m] = accA[m][n] + blv[m];
          mx = fmaxf(mx, fmaxf(fmaxf(v[m].x, v[m].y), fmaxf(v[m].z, v[m].w)));
        }
        mx = fmaxf(mx, __shfl_xor(mx,16));
        mx = fmaxf(mx, __shfl_xor(mx,32));
        float s = 0.f;
        #pragma unroll
        for (int m=0;m<4;m++){
          v[m].x = __expf(v[m].x-mx); v[m].y = __expf(v[m].y-mx);
          v[m].z = __expf(v[m].z-mx); v[m].w = __expf(v[m].w-mx);
          s += v[m].x+v[m].y+v[m].z+v[m].w;
        }
        s += __shfl_xor(s,16);
        s += __shfl_xor(s,32);
        const float inv = 1.0f/s;
        const long gn = gn0 + (((nh<<2)+n)<<4) + c16;
        #pragma unroll
        for (int m=0;m<4;m++){
          f32x4 sv = v[m]*inv;
          nacc[m] += sv;
          u32x2 p; p.x = pk2(sv.x, sv.y); p.y = pk2(sv.z, sv.w);
          *(u32x2*)(swg + (gn<<9) + (w<<6)+(m<<4)+(rg<<2)) = p;
          if (nh==0){
            // pair-pack transpose (regs=m) -> swL [m][pt], immediately (no pk liveness)
            const uint32 px = (uint32)__shfl_xor((int)p.x, 1);
            const uint32 py = (uint32)__shfl_xor((int)p.y, 1);
            const bool ev = ((c16&1)==0);
            const uint32 s0 = ev ? (uint32)p.x : py;
            const uint32 s1 = ev ? px : (uint32)p.y;
            const uint32 wA = (s0 & 0xffffu) | (s1<<16);
            const uint32 wB = (s0>>16) | (s1 & 0xffff0000u);
            const int rowA = (m<<4) + (rg<<2) + (ev?0:2);
            const int cbyt = ((n<<4) + (c16 & ~1)) << 1;
            *(uint32*)(swb + ((rowA  )<<7) + (cbyt ^ (((rowA  )&7)<<4))) = wA;
            *(uint32*)(swb + ((rowA+1)<<7) + (cbyt ^ (((rowA+1)&7)<<4))) = wB;
          } else {
            pk1[m][n] = p;
          }
        }
      }
    }

    // ---- Phase B (fx = X @ Wfx): D rows = points (regs), cols = channels (lanes) ----
    u32x2 qkh[2][8], qkl[2][8];   // fx hi/lo bf16 per (c-block, pt-block)
    #pragma unroll
    for (int rh=0; rh<2; rh++){
      f32x4 accB[4][2];
      #pragma unroll
      for (int r=0;r<4;r++)
        #pragma unroll
        for (int c=0;c<2;c++) accB[r][c] = (f32x4){0.f,0.f,0.f,0.f};
      #pragma unroll
      for (int kb=0;kb<8;kb++){
        s16x8 bW[2], aX[4];
        #pragma unroll
        for (int c=0;c<2;c++)
          bW[c] = *(const s16x8*)(WfxT + (((w<<5)+(c<<4)+c16)<<8) + (kb<<5)+(rg<<3));
        #pragma unroll
        for (int r=0;r<4;r++){
          const int row = (((rh<<2)+r)<<4) | c16;
          aX[r] = *(const s16x8*)(smem + (row<<9) + (((kb<<6)+(rg<<4)) ^ ((row&7)<<4)));
        }
        #pragma unroll
        for (int r=0;r<4;r++)
          #pragma unroll
          for (int c=0;c<2;c++)
            accB[r][c] = mfma16(aX[r], bW[c], accB[r][c]);
      }
      #pragma unroll
      for (int r=0;r<4;r++)
        #pragma unroll
        for (int c=0;c<2;c++){
          const float v0 = accB[r][c].x+bfv[c], v1 = accB[r][c].y+bfv[c];
          const float v2 = accB[r][c].z+bfv[c], v3 = accB[r][c].w+bfv[c];
          const uint32 h0=f2bf(v0), h1=f2bf(v1), h2=f2bf(v2), h3=f2bf(v3);
          u32x2 ph; ph.x = h0|(h1<<16); ph.y = h2|(h3<<16);
          qkh[c][(rh<<2)+r] = ph;
          u32x2 pl;
          pl.x = f2bf(v0-bfl(h0)) | (f2bf(v1-bfl(h1))<<16);
          pl.y = f2bf(v2-bfl(h2)) | (f2bf(v3-bfl(h3))<<16);
          qkl[c][(rh<<2)+r] = pl;
        }
    }
    __syncthreads();   // S3: all waves done reading X -> fx overlay allowed

    // ---- stage fx(h0) hi/lo into overlay ----
    #pragma unroll
    for (int cf=0; cf<2; cf++)
      #pragma unroll
      for (int nb=0; nb<4; nb++){
        const int row = (cf<<4) + c16;
        const int cby = ((nb<<5) + (rg<<3)) ^ ((row&7)<<4);
        *(u32x2*)(fxh + (row<<7) + cby) = qkh[cf][nb];
        *(u32x2*)(fxl + (row<<7) + cby) = qkl[cf][nb];
      }
    asm volatile("s_waitcnt lgkmcnt(0)" ::: "memory");
    __builtin_amdgcn_sched_barrier(0);

    // ---- Phase C, half 0 ----
    #pragma unroll
    for (int kb2=0; kb2<2; kb2++){
      const int pby = (kb2<<6) + (rg<<4);
      s16x8 afh[2], afl[2], bfr[4];
      #pragma unroll
      for (int cf=0; cf<2; cf++){
        const int row = (cf<<4)+c16;
        const int o = pby ^ ((row&7)<<4);
        afh[cf] = *(const s16x8*)(fxh + (row<<7) + o);
        afl[cf] = *(const s16x8*)(fxl + (row<<7) + o);
      }
      #pragma unroll
      for (int mf=0; mf<4; mf++){
        const int row = (mf<<4)+c16;
        bfr[mf] = *(const s16x8*)(swb + (row<<7) + (pby ^ ((row&7)<<4)));
      }
      #pragma unroll
      for (int cf=0; cf<2; cf++)
        #pragma unroll
        for (int mf=0; mf<4; mf++){
          pc[cf][mf] = mfma16(afh[cf], bfr[mf], pc[cf][mf]);
          pc[cf][mf] = mfma16(afl[cf], bfr[mf], pc[cf][mf]);
        }
    }
    asm volatile("s_waitcnt lgkmcnt(0)" ::: "memory");   // C(h0) LDS reads done before overwrite
    __builtin_amdgcn_sched_barrier(0);

    // ---- stage sw(h1) from pk1 (wave-private overwrite of swL) ----
    #pragma unroll
    for (int mb=0; mb<4; mb++)
      #pragma unroll
      for (int nb=0; nb<4; nb++){
        u32x2 d = pk1[mb][nb];
        const uint32 px = (uint32)__shfl_xor((int)d.x, 1);
        const uint32 py = (uint32)__shfl_xor((int)d.y, 1);
        const bool ev = ((c16&1)==0);
        const uint32 s0 = ev ? (uint32)d.x : py;
        const uint32 s1 = ev ? px : (uint32)d.y;
        const uint32 wA = (s0 & 0xffffu) | (s1<<16);
        const uint32 wB = (s0>>16) | (s1 & 0xffff0000u);
        const int rowA = (mb<<4) + (rg<<2) + (ev?0:2);
        const int cbyt = ((nb<<4) + (c16 & ~1)) << 1;
        *(uint32*)(swb + ((rowA  )<<7) + (cbyt ^ (((rowA  )&7)<<4))) = wA;
        *(uint32*)(swb + ((rowA+1)<<7) + (cbyt ^ (((rowA+1)&7)<<4))) = wB;
      }
    // ---- stage fx(h1) (overwrite overlay) ----
    #pragma unroll
    for (int cf=0; cf<2; cf++)
      #pragma unroll
      for (int nb=0; nb<4; nb++){
        const int row = (cf<<4) + c16;
        const int cby = ((nb<<5) + (rg<<3)) ^ ((row&7)<<4);
        *(u32x2*)(fxh + (row<<7) + cby) = qkh[cf][4+nb];
        *(u32x2*)(fxl + (row<<7) + cby) = qkl[cf][4+nb];
      }
    asm volatile("s_waitcnt lgkmcnt(0)" ::: "memory");
    __builtin_amdgcn_sched_barrier(0);

    // ---- Phase C, half 1 ----
    #pragma unroll
    for (int kb2=0; kb2<2; kb2++){
      const int pby = (kb2<<6) + (rg<<4);
      s16x8 afh[2], afl[2], bfr[4];
      #pragma unroll
      for (int cf=0; cf<2; cf++){
        const int row = (cf<<4)+c16;
        const int o = pby ^ ((row&7)<<4);
        afh[cf] = *(const s16x8*)(fxh + (row<<7) + o);
        afl[cf] = *(const s16x8*)(fxl + (row<<7) + o);
      }
      #pragma unroll
      for (int mf=0; mf<4; mf++){
        const int row = (mf<<4)+c16;
        bfr[mf] = *(const s16x8*)(swb + (row<<7) + (pby ^ ((row&7)<<4)));
      }
      #pragma unroll
      for (int cf=0; cf<2; cf++)
        #pragma unroll
        for (int mf=0; mf<4; mf++){
          pc[cf][mf] = mfma16(afh[cf], bfr[mf], pc[cf][mf]);
          pc[cf][mf] = mfma16(afl[cf], bfr[mf], pc[cf][mf]);
        }
    }
  } // tiles

  // ---- epilogue: norm reduce + stores ----
  #pragma unroll
  for (int m=0;m<4;m++){
    #pragma unroll
    for (int d=1; d<16; d<<=1){
      nacc[m].x += __shfl_xor(nacc[m].x, d);
      nacc[m].y += __shfl_xor(nacc[m].y, d);
      nacc[m].z += __shfl_xor(nacc[m].z, d);
      nacc[m].w += __shfl_xor(nacc[m].w, d);
    }
  }
  if (c16==0){
    #pragma unroll
    for (int m=0;m<4;m++)
      *(f32x4*)(normp + (((blk<<3)+w)<<6) + (m<<4) + (rg<<2)) = nacc[m];
  }
  const long sb = ((long)((blk<<3)+w))<<11;   // stp[blk][w][32 c][64 m]
  #pragma unroll
  for (int cf=0;cf<2;cf++)
    #pragma unroll
    for (int mf=0;mf<4;mf++)
      #pragma unroll
      for (int r=0;r<4;r++){
        const int cc = (cf<<4)+(rg<<2)+r;
        stp[sb + (cc<<6) + (mf<<4) + c16] = pc[cf][mf][r];
      }
}

// ---------------- k2a: hierarchical partial reduce (in-place into chunk-slot grp*16) ----------------
__global__ __launch_bounds__(256) void k2a_kernel(float* __restrict__ stp, float* __restrict__ normp)
{
  const int gid = blockIdx.x;           // 128 = 16 bh * 8 grp
  const int bh = gid>>3, grp = gid&7;
  const int b = bh>>3, h = bh&7;
  const int t = threadIdx.x;
  const int blk0 = (b<<7) + (grp<<4);
  f32x4 a0 = {0,0,0,0}, a1 = {0,0,0,0};
  for (int i=0;i<16;i++){
    const f32x4* p = (const f32x4*)(stp + ((((size_t)(blk0+i)<<3)+h)<<11) + ((size_t)t<<3));
    a0 += p[0]; a1 += p[1];
  }
  f32x4* q = (f32x4*)(stp + ((((size_t)blk0<<3)+h)<<11) + ((size_t)t<<3));
  q[0] = a0; q[1] = a1;
  if (t<8){
    f32x4 n0 = {0,0,0,0}, n1 = {0,0,0,0};
    for (int i=0;i<16;i++){
      const f32x4* p = (const f32x4*)(normp + (((blk0+i)<<3)+h)*64 + (t<<3));
      n0 += p[0]; n1 += p[1];
    }
    f32x4* qn = (f32x4*)(normp + ((blk0<<3)+h)*64 + (t<<3));
    qn[0] = n0; qn[1] = n1;
  }
}

// ---------------- k2b: final reduce + tiny attention + fold W_out -> OS2T hi/lo bf16 ----------------
__global__ __launch_bounds__(256) void k2b_kernel(
    const float* __restrict__ stp, const float* __restrict__ normp,
    const float* __restrict__ Wq, const float* __restrict__ Wk, const float* __restrict__ Wv,
    const float* __restrict__ Wout, ushort* __restrict__ OS2Th, ushort* __restrict__ OS2Tl)
{
  __shared__ float nrmL[64];
  __shared__ float tok[2048];
  __shared__ float qL[2048], kL[2048], vL[2048];
  __shared__ float sc[4096];
  __shared__ float osL[2048];
  const int bh = blockIdx.x; const int b = bh>>3, h = bh&7;
  const int t = threadIdx.x;

  if (t<64){
    float s = 0.f;
    for (int g=0; g<8; g++) s += normp[((((b<<7)+(g<<4))<<3)+h)*64 + t];
    nrmL[t] = s;
  }
  __syncthreads();
  {
    f32x4 a0 = {0,0,0,0}, a1 = {0,0,0,0};
    for (int g=0; g<8; g++){
      const f32x4* p = (const f32x4*)(stp + ((((size_t)((b<<7)+(g<<4))<<3)+h)<<11) + ((size_t)t<<3));
      a0 += p[0]; a1 += p[1];
    }
    const int c = t>>3, m0 = (t&7)<<3;
    #pragma unroll
    for (int j=0;j<4;j++) tok[(m0+j)*32 + c]   = a0[j] / (nrmL[m0+j]   + 1e-5f);
    #pragma unroll
    for (int j=0;j<4;j++) tok[(m0+4+j)*32 + c] = a1[j] / (nrmL[m0+4+j] + 1e-5f);
  }
  __syncthreads();

  const int g = t>>2, q4 = t&3;
  float aq[8]={0,0,0,0,0,0,0,0}, ak2[8]={0,0,0,0,0,0,0,0}, av[8]={0,0,0,0,0,0,0,0};
  for (int kk=0; kk<32; kk++){
    const float tv = tok[(g<<5)+kk];
    const int wo = kk*32 + (q4<<3);
    #pragma unroll
    for (int j=0;j<8;j++){
      aq[j]  = fmaf(tv, Wq[wo+j], aq[j]);
      ak2[j] = fmaf(tv, Wk[wo+j], ak2[j]);
      av[j]  = fmaf(tv, Wv[wo+j], av[j]);
    }
  }
  #pragma unroll
  for (int j=0;j<8;j++){
    qL[(g<<5)+(q4<<3)+j]=aq[j];
    kL[(g<<5)+(q4<<3)+j]=ak2[j];
    vL[(g<<5)+(q4<<3)+j]=av[j];
  }
  __syncthreads();

  const float scale = 0.17677669529663689f;
  float svv[16]; float mx = -3.0e38f;
  for (int mm=0;mm<16;mm++){
    const int m = (q4<<4)+mm;
    float s2 = 0.f;
    #pragma unroll
    for (int c=0;c<32;c++) s2 = fmaf(qL[(g<<5)+c], kL[(m<<5)+c], s2);
    s2 *= scale;
    svv[mm] = s2; mx = fmaxf(mx, s2);
  }
  mx = fmaxf(mx, __shfl_xor(mx,1));
  mx = fmaxf(mx, __shfl_xor(mx,2));
  float ssum = 0.f;
  for (int mm=0;mm<16;mm++){ svv[mm] = __expf(svv[mm]-mx); ssum += svv[mm]; }
  ssum += __shfl_xor(ssum,1); ssum += __shfl_xor(ssum,2);
  const float isum = 1.0f/ssum;
  for (int mm=0;mm<16;mm++) sc[(g<<6) + (q4<<4) + mm] = svv[mm]*isum;
  __syncthreads();

  float os[8]={0,0,0,0,0,0,0,0};
  for (int m=0;m<64;m++){
    const float a = sc[(g<<6)+m];
    const int vo = (m<<5)+(q4<<3);
    #pragma unroll
    for (int j=0;j<8;j++) os[j] = fmaf(a, vL[vo+j], os[j]);
  }
  #pragma unroll
  for (int j=0;j<8;j++) osL[(g<<5)+(q4<<3)+j] = os[j];
  __syncthreads();

  // OS2T{h,l}[b][d][h*64+g] = sum_c os[g][c] * Wout[h*32+c][d]  (split bf16)
  const int d = t;
  float wcol[32];
  #pragma unroll
  for (int c=0;c<32;c++) wcol[c] = Wout[(h*32+c)*256 + d];
  uint32* orh = (uint32*)(OS2Th + ((size_t)(b*256+d))*512 + h*64);
  uint32* orl = (uint32*)(OS2Tl + ((size_t)(b*256+d))*512 + h*64);
  #pragma unroll 4
  for (int g2=0; g2<32; g2++){
    float s0=0.f, s1=0.f;
    #pragma unroll
    for (int c=0;c<32;c++){
      s0 = fmaf(osL[((g2*2  )<<5)+c], wcol[c], s0);
      s1 = fmaf(osL[((g2*2+1)<<5)+c], wcol[c], s1);
    }
    const uint32 h0 = f2bf(s0), h1 = f2bf(s1);
    orh[g2] = h0 | (h1<<16);
    orl[g2] = f2bf(s0 - bfl(h0)) | (f2bf(s1 - bfl(h1)) << 16);
  }
}

// ---------------- k3: out = swg @ (OS2Th+OS2Tl)^T + b_out (register MFMA GEMM) ----------------
__global__ __launch_bounds__(256) void k3_kernel(
    const ushort* __restrict__ swg,
    const ushort* __restrict__ OS2Th,
    const ushort* __restrict__ OS2Tl,
    const float* __restrict__ bout,
    float* __restrict__ out)
{
  const int t = threadIdx.x, w = t>>6, l = t&63, rg = l>>4, c16 = l&15;
  const int blk = blockIdx.x;
  const long gn0 = (long)blk<<7;
  const int b = blk>>9;
  f32x4 acc[8][4];
  #pragma unroll
  for (int r=0;r<8;r++)
    #pragma unroll
    for (int c=0;c<4;c++) acc[r][c] = (f32x4){0.f,0.f,0.f,0.f};
  const ushort* swp = swg + (gn0<<9);
  const long obb = (((long)(b<<8) + (w<<6))<<9);
  for (int kb=0;kb<16;kb++){
    s16x8 aS[8];
    #pragma unroll
    for (int r=0;r<8;r++)
      aS[r] = *(const s16x8*)(swp + ((long)((r<<4)+c16)<<9) + (kb<<5)+(rg<<3));
    #pragma unroll
    for (int c=0;c<4;c++){
      const long ro = obb + ((long)((c<<4)+c16)<<9) + (kb<<5)+(rg<<3);
      const s16x8 bh = *(const s16x8*)(OS2Th + ro);
      const s16x8 bl = *(const s16x8*)(OS2Tl + ro);
      #pragma unroll
      for (int r=0;r<8;r++)
        acc[r][c] = mfma16(aS[r], bh, acc[r][c]);
      #pragma unroll
      for (int r=0;r<8;r++)
        acc[r][c] = mfma16(aS[r], bl, acc[r][c]);
    }
  }
  float bo[4];
  #pragma unroll
  for (int c=0;c<4;c++) bo[c] = bout[(w<<6)+(c<<4)+c16];
  #pragma unroll
  for (int r=0;r<8;r++)
    #pragma unroll
    for (int c=0;c<4;c++)
      #pragma unroll
      for (int rr=0;rr<4;rr++)
        out[((gn0 + (r<<4)+(rg<<2)+rr)<<8) + (w<<6)+(c<<4)+c16] = acc[r][c][rr] + bo[c];
}

extern "C" void kernel_launch(void* const* d_in, const int* in_sizes, int n_in,
                              void* d_out, int out_size, void* d_ws, size_t ws_size,
                              hipStream_t stream)
{
  const float* x     = (const float*)d_in[0];
  const float* Wfx   = (const float*)d_in[1];
  const float* bfx   = (const float*)d_in[2];
  const float* Wx    = (const float*)d_in[3];
  const float* bx    = (const float*)d_in[4];
  const float* Wsl   = (const float*)d_in[5];
  const float* bsl   = (const float*)d_in[6];
  const float* temp  = (const float*)d_in[7];
  const float* Wq    = (const float*)d_in[8];
  const float* Wk    = (const float*)d_in[9];
  const float* Wv    = (const float*)d_in[10];
  const float* Wout  = (const float*)d_in[11];
  const float* bout  = (const float*)d_in[12];
  float* out = (float*)d_out;

  char* ws = (char*)d_ws;
  // ws layout (bytes), total 152,963,072:
  ushort* WlT   = (ushort*)(ws);                   // 262144
  ushort* WfxT  = (ushort*)(ws + 262144);          // 131072
  float*  blT   = (float*) (ws + 393216);          // 2048
  ushort* swg   = (ushort*)(ws + 395264);          // 134217728
  float*  stp   = (float*) (ws + 134612992);       // 16777216
  float*  normp = (float*) (ws + 151390208);       // 524288
  ushort* OS2Th = (ushort*)(ws + 151914496);       // 524288
  ushort* OS2Tl = (ushort*)(ws + 152438784);       // 524288

  prep_kernel<<<dim3(768), dim3(256), 0, stream>>>(Wfx, Wx, Wsl, bsl, bx, temp, WlT, WfxT, blT);
  k1a_kernel<<<dim3(256), dim3(512), 0, stream>>>(x, WlT, WfxT, blT, bfx, swg, stp, normp);
  k2a_kernel<<<dim3(128), dim3(256), 0, stream>>>(stp, normp);
  k2b_kernel<<<dim3(16), dim3(256), 0, stream>>>(stp, normp, Wq, Wk, Wv, Wout, OS2Th, OS2Tl);
  k3_kernel<<<dim3(1024), dim3(256), 0, stream>>>(swg, OS2Th, OS2Tl, bout, out);
}

// Round 5
// 457.137 us; speedup vs baseline: 2.6797x; 1.0875x over previous
//
#include <hip/hip_runtime.h>

#define N_ 65536

typedef unsigned int  uint32;
typedef unsigned short ushort;
typedef float  f32x4 __attribute__((ext_vector_type(4)));
typedef short  s16x8 __attribute__((ext_vector_type(8)));
typedef uint32 u32x2 __attribute__((ext_vector_type(2)));

__device__ __forceinline__ uint32 f2bf(float f){
  union{float f; uint32 i;} v; v.f=f;
  return (v.i + 0x7fffu + ((v.i>>16)&1u)) >> 16;   // RNE
}
__device__ __forceinline__ float bfl(uint32 h){     // bf16 (low 16 bits) -> float
  union{uint32 i; float f;} v; v.i = h<<16; return v.f;
}
__device__ __forceinline__ uint32 pk2(float a, float b){
  return f2bf(a) | (f2bf(b)<<16);
}
__device__ __forceinline__ f32x4 mfma16(s16x8 a, s16x8 b, f32x4 c){
  return __builtin_amdgcn_mfma_f32_16x16x32_bf16(a,b,c,0,0,0);
}

// ---------------- prep: WlT[512][256], WfxT[256][256] (bf16, k-inner), blT[512] ----------------
__global__ __launch_bounds__(256) void prep_kernel(
    const float* __restrict__ Wfx, const float* __restrict__ Wx,
    const float* __restrict__ Wsl, const float* __restrict__ bsl,
    const float* __restrict__ bx,  const float* __restrict__ temp,
    ushort* __restrict__ WlT, ushort* __restrict__ WfxT, float* __restrict__ blT)
{
  const int blk = blockIdx.x, t = threadIdx.x;
  if (blk < 512){
    const int m = blk, h = m>>6, mp = m&63;
    const float tmp = fminf(fmaxf(temp[h],0.1f),5.0f);
    float s = 0.f;
    #pragma unroll
    for (int cc=0; cc<32; cc++) s += Wx[t*256 + h*32+cc]*Wsl[cc*64+mp];
    WlT[m*256+t] = (ushort)f2bf(s/tmp);
    if (t==0){
      float bs = bsl[mp];
      for (int cc=0; cc<32; cc++) bs += bx[h*32+cc]*Wsl[cc*64+mp];
      blT[m] = bs/tmp;
    }
  } else {
    const int c = blk-512;
    WfxT[c*256+t] = (ushort)f2bf(Wfx[t*256+c]);
  }
}

// ---------------- k1a: fused proj + softmax + slice-token partials ----------------
// 64-pt tiles, 8 per block. LDS map (128 KiB):
//   [0,32K):   X tile [64 pt][512B] swizzled; after S3 per-wave fxh overlay at w*4K
//   [32K,96K): per-wave swL at 32K+w*8K: [64 m][128B] swizzled (wave-private)
//   [96K,128K): per-wave fxl at 96K+w*4K: [32 c][128B] swizzled (wave-private)
__global__ __launch_bounds__(512) __attribute__((amdgpu_waves_per_eu(2,2)))
void k1a_kernel(
    const float* __restrict__ x,
    const ushort* __restrict__ WlT,
    const ushort* __restrict__ WfxT,
    const float* __restrict__ blT,
    const float* __restrict__ bfx,
    ushort* __restrict__ swg,       // [B*N][512] bf16 (m-inner)
    float* __restrict__ stp,        // [256][8][32][64] f32
    float* __restrict__ normp)      // [256][8][64]
{
  __shared__ __align__(16) char smem[131072];
  const int t = threadIdx.x;
  const int w = t>>6, l = t&63, rg = l>>4, c16 = l&15;
  const int blk = blockIdx.x;
  const int tile0 = ((blk&127)<<3) + ((blk>>7)<<10);

  char* fxh = smem + (w<<12);             // 4 KB per wave (X overlay, post-S3)
  char* swb = smem + 32768 + (w<<13);     // 8 KB per wave
  char* fxl = smem + 98304 + (w<<12);     // 4 KB per wave (dedicated)

  f32x4 pc[2][4];      // Phase C accumulators: [c-frag][m-frag]
  #pragma unroll
  for (int i=0;i<2;i++)
    #pragma unroll
    for (int j=0;j<4;j++) pc[i][j] = (f32x4){0.f,0.f,0.f,0.f};
  f32x4 nacc[4];
  #pragma unroll
  for (int i=0;i<4;i++) nacc[i] = (f32x4){0.f,0.f,0.f,0.f};

  f32x4 blv[4];
  #pragma unroll
  for (int m=0;m<4;m++) blv[m] = *(const f32x4*)(blT + (w<<6)+(m<<4)+(rg<<2));
  float bfv[2];
  #pragma unroll
  for (int c=0;c<2;c++) bfv[c] = bfx[(w<<5)+(c<<4)+c16];

  for (int it=0; it<8; ++it) {
    const int tile = tile0 + it;
    const long gn0 = (long)tile<<6;

    __syncthreads();   // S1: prev tile's Phase-C reads (incl. fxh overlay) done
    // ---- stage X tile [64][256] -> bf16 LDS, XOR-swizzled ----
    {
      const float4* xs = (const float4*)(x + (gn0<<8));
      #pragma unroll
      for (int p=0;p<8;p++){
        const int f = t + (p<<9);
        const int row = f>>6, q = f&63;
        const float4 v = xs[f];
        u32x2 uu; uu.x = pk2(v.x, v.y); uu.y = pk2(v.z, v.w);
        *(u32x2*)(smem + (row<<9) + ((q<<3) ^ ((row&7)<<4))) = uu;
      }
    }
    __syncthreads();   // S2: X ready

    // ---- Phase A (logits^T = WlT @ X^T) in two 32-pt chunks; sw staged inline ----
    #pragma unroll
    for (int ch=0; ch<2; ch++){
      f32x4 accA[4][2];
      #pragma unroll
      for (int m=0;m<4;m++)
        #pragma unroll
        for (int n=0;n<2;n++) accA[m][n] = (f32x4){0.f,0.f,0.f,0.f};
      #pragma unroll
      for (int kb=0;kb<8;kb++){
        s16x8 aW[4], bX[2];
        #pragma unroll
        for (int m=0;m<4;m++)
          aW[m] = *(const s16x8*)(WlT + (((w<<6)+(m<<4)+c16)<<8) + (kb<<5)+(rg<<3));
        #pragma unroll
        for (int n=0;n<2;n++){
          const int row = (ch<<5) + (n<<4) + c16;
          bX[n] = *(const s16x8*)(smem + (row<<9) + (((kb<<6)+(rg<<4)) ^ ((row&7)<<4)));
        }
        #pragma unroll
        for (int m=0;m<4;m++)
          #pragma unroll
          for (int n=0;n<2;n++)
            accA[m][n] = mfma16(aW[m], bX[n], accA[m][n]);
      }
      // softmax over m (4 m-frags in-reg x 4 rg-groups cross-lane), per pt column
      #pragma unroll
      for (int n=0;n<2;n++){
        const int nf = (ch<<1) + n;      // pt-frag index in tile (0..3)
        f32x4 v[4];
        float mx = -3.0e38f;
        #pragma unroll
        for (int m=0;m<4;m++){
          v[m] = accA[m][n] + blv[m];
          mx = fmaxf(mx, fmaxf(fmaxf(v[m].x, v[m].y), fmaxf(v[m].z, v[m].w)));
        }
        mx = fmaxf(mx, __shfl_xor(mx,16));
        mx = fmaxf(mx, __shfl_xor(mx,32));
        float s = 0.f;
        #pragma unroll
        for (int m=0;m<4;m++){
          v[m].x = __expf(v[m].x-mx); v[m].y = __expf(v[m].y-mx);
          v[m].z = __expf(v[m].z-mx); v[m].w = __expf(v[m].w-mx);
          s += v[m].x+v[m].y+v[m].z+v[m].w;
        }
        s += __shfl_xor(s,16);
        s += __shfl_xor(s,32);
        const float inv = 1.0f/s;
        const long gn = gn0 + (nf<<4) + c16;
        #pragma unroll
        for (int m=0;m<4;m++){
          f32x4 sv = v[m]*inv;
          nacc[m] += sv;
          u32x2 p; p.x = pk2(sv.x, sv.y); p.y = pk2(sv.z, sv.w);
          *(u32x2*)(swg + (gn<<9) + (w<<6)+(m<<4)+(rg<<2)) = p;
          // pair-pack transpose (regs=m) -> swL [m][pt], immediately (no persistence)
          const uint32 px = (uint32)__shfl_xor((int)p.x, 1);
          const uint32 py = (uint32)__shfl_xor((int)p.y, 1);
          const bool ev = ((c16&1)==0);
          const uint32 s0 = ev ? (uint32)p.x : py;
          const uint32 s1 = ev ? px : (uint32)p.y;
          const uint32 wA = (s0 & 0xffffu) | (s1<<16);
          const uint32 wB = (s0>>16) | (s1 & 0xffff0000u);
          const int rowA = (m<<4) + (rg<<2) + (ev?0:2);
          const int cbyt = ((nf<<4) + (c16 & ~1)) << 1;
          *(uint32*)(swb + ((rowA  )<<7) + (cbyt ^ (((rowA  )&7)<<4))) = wA;
          *(uint32*)(swb + ((rowA+1)<<7) + (cbyt ^ (((rowA+1)&7)<<4))) = wB;
        }
      }
    }

    // ---- Phase B (fx = X @ Wfx): hi kept in regs (16), lo staged to LDS directly ----
    u32x2 qkh[2][4];
    {
      f32x4 accB[4][2];
      #pragma unroll
      for (int r=0;r<4;r++)
        #pragma unroll
        for (int c=0;c<2;c++) accB[r][c] = (f32x4){0.f,0.f,0.f,0.f};
      #pragma unroll
      for (int kb=0;kb<8;kb++){
        s16x8 bW[2], aX[4];
        #pragma unroll
        for (int c=0;c<2;c++)
          bW[c] = *(const s16x8*)(WfxT + (((w<<5)+(c<<4)+c16)<<8) + (kb<<5)+(rg<<3));
        #pragma unroll
        for (int r=0;r<4;r++){
          const int row = (r<<4) | c16;
          aX[r] = *(const s16x8*)(smem + (row<<9) + (((kb<<6)+(rg<<4)) ^ ((row&7)<<4)));
        }
        #pragma unroll
        for (int r=0;r<4;r++)
          #pragma unroll
          for (int c=0;c<2;c++)
            accB[r][c] = mfma16(aX[r], bW[c], accB[r][c]);
      }
      #pragma unroll
      for (int r=0;r<4;r++)
        #pragma unroll
        for (int c=0;c<2;c++){
          const float v0 = accB[r][c].x+bfv[c], v1 = accB[r][c].y+bfv[c];
          const float v2 = accB[r][c].z+bfv[c], v3 = accB[r][c].w+bfv[c];
          const uint32 h0=f2bf(v0), h1=f2bf(v1), h2=f2bf(v2), h3=f2bf(v3);
          u32x2 ph; ph.x = h0|(h1<<16); ph.y = h2|(h3<<16);
          qkh[c][r] = ph;
          u32x2 pl;
          pl.x = f2bf(v0-bfl(h0)) | (f2bf(v1-bfl(h1))<<16);
          pl.y = f2bf(v2-bfl(h2)) | (f2bf(v3-bfl(h3))<<16);
          const int row = (c<<4) + c16;
          const int cby = ((r<<5) + (rg<<3)) ^ ((row&7)<<4);
          *(u32x2*)(fxl + (row<<7) + cby) = pl;
        }
    }
    __syncthreads();   // S3: all waves done reading X -> fxh overlay allowed

    // ---- stage fx-hi into overlay ----
    #pragma unroll
    for (int cf=0; cf<2; cf++)
      #pragma unroll
      for (int r=0; r<4; r++){
        const int row = (cf<<4) + c16;
        const int cby = ((r<<5) + (rg<<3)) ^ ((row&7)<<4);
        *(u32x2*)(fxh + (row<<7) + cby) = qkh[cf][r];
      }
    asm volatile("s_waitcnt lgkmcnt(0)" ::: "memory");
    __builtin_amdgcn_sched_barrier(0);

    // ---- Phase C: pc[c][m] += fx^T-frag @ sw-frag ----
    #pragma unroll
    for (int kb2=0; kb2<2; kb2++){
      const int pby = (kb2<<6) + (rg<<4);
      s16x8 afh[2], afl[2], bfr[4];
      #pragma unroll
      for (int cf=0; cf<2; cf++){
        const int row = (cf<<4)+c16;
        const int o = pby ^ ((row&7)<<4);
        afh[cf] = *(const s16x8*)(fxh + (row<<7) + o);
        afl[cf] = *(const s16x8*)(fxl + (row<<7) + o);
      }
      #pragma unroll
      for (int mf=0; mf<4; mf++){
        const int row = (mf<<4)+c16;
        bfr[mf] = *(const s16x8*)(swb + (row<<7) + (pby ^ ((row&7)<<4)));
      }
      #pragma unroll
      for (int cf=0; cf<2; cf++)
        #pragma unroll
        for (int mf=0; mf<4; mf++){
          pc[cf][mf] = mfma16(afh[cf], bfr[mf], pc[cf][mf]);
          pc[cf][mf] = mfma16(afl[cf], bfr[mf], pc[cf][mf]);
        }
    }
  } // tiles

  // ---- epilogue: norm reduce + stores ----
  #pragma unroll
  for (int m=0;m<4;m++){
    #pragma unroll
    for (int d=1; d<16; d<<=1){
      nacc[m].x += __shfl_xor(nacc[m].x, d);
      nacc[m].y += __shfl_xor(nacc[m].y, d);
      nacc[m].z += __shfl_xor(nacc[m].z, d);
      nacc[m].w += __shfl_xor(nacc[m].w, d);
    }
  }
  if (c16==0){
    #pragma unroll
    for (int m=0;m<4;m++)
      *(f32x4*)(normp + (((blk<<3)+w)<<6) + (m<<4) + (rg<<2)) = nacc[m];
  }
  const long sb = ((long)((blk<<3)+w))<<11;   // stp[blk][w][32 c][64 m]
  #pragma unroll
  for (int cf=0;cf<2;cf++)
    #pragma unroll
    for (int mf=0;mf<4;mf++)
      #pragma unroll
      for (int r=0;r<4;r++){
        const int cc = (cf<<4)+(rg<<2)+r;
        stp[sb + (cc<<6) + (mf<<4) + c16] = pc[cf][mf][r];
      }
}

// ---------------- k2a: hierarchical partial reduce (in-place into chunk-slot grp*16) ----------------
__global__ __launch_bounds__(256) void k2a_kernel(float* __restrict__ stp, float* __restrict__ normp)
{
  const int gid = blockIdx.x;           // 128 = 16 bh * 8 grp
  const int bh = gid>>3, grp = gid&7;
  const int b = bh>>3, h = bh&7;
  const int t = threadIdx.x;
  const int blk0 = (b<<7) + (grp<<4);
  f32x4 a0 = {0,0,0,0}, a1 = {0,0,0,0};
  for (int i=0;i<16;i++){
    const f32x4* p = (const f32x4*)(stp + ((((size_t)(blk0+i)<<3)+h)<<11) + ((size_t)t<<3));
    a0 += p[0]; a1 += p[1];
  }
  f32x4* q = (f32x4*)(stp + ((((size_t)blk0<<3)+h)<<11) + ((size_t)t<<3));
  q[0] = a0; q[1] = a1;
  if (t<8){
    f32x4 n0 = {0,0,0,0}, n1 = {0,0,0,0};
    for (int i=0;i<16;i++){
      const f32x4* p = (const f32x4*)(normp + (((blk0+i)<<3)+h)*64 + (t<<3));
      n0 += p[0]; n1 += p[1];
    }
    f32x4* qn = (f32x4*)(normp + ((blk0<<3)+h)*64 + (t<<3));
    qn[0] = n0; qn[1] = n1;
  }
}

// ---------------- k2b: final reduce + tiny attention + fold W_out -> OS2T hi/lo bf16 ----------------
__global__ __launch_bounds__(256) void k2b_kernel(
    const float* __restrict__ stp, const float* __restrict__ normp,
    const float* __restrict__ Wq, const float* __restrict__ Wk, const float* __restrict__ Wv,
    const float* __restrict__ Wout, ushort* __restrict__ OS2Th, ushort* __restrict__ OS2Tl)
{
  __shared__ float nrmL[64];
  __shared__ float tok[2048];
  __shared__ float qL[2048], kL[2048], vL[2048];
  __shared__ float sc[4096];
  __shared__ float osL[2048];
  const int bh = blockIdx.x; const int b = bh>>3, h = bh&7;
  const int t = threadIdx.x;

  if (t<64){
    float s = 0.f;
    for (int g=0; g<8; g++) s += normp[((((b<<7)+(g<<4))<<3)+h)*64 + t];
    nrmL[t] = s;
  }
  __syncthreads();
  {
    f32x4 a0 = {0,0,0,0}, a1 = {0,0,0,0};
    for (int g=0; g<8; g++){
      const f32x4* p = (const f32x4*)(stp + ((((size_t)((b<<7)+(g<<4))<<3)+h)<<11) + ((size_t)t<<3));
      a0 += p[0]; a1 += p[1];
    }
    const int c = t>>3, m0 = (t&7)<<3;
    #pragma unroll
    for (int j=0;j<4;j++) tok[(m0+j)*32 + c]   = a0[j] / (nrmL[m0+j]   + 1e-5f);
    #pragma unroll
    for (int j=0;j<4;j++) tok[(m0+4+j)*32 + c] = a1[j] / (nrmL[m0+4+j] + 1e-5f);
  }
  __syncthreads();

  const int g = t>>2, q4 = t&3;
  float aq[8]={0,0,0,0,0,0,0,0}, ak2[8]={0,0,0,0,0,0,0,0}, av[8]={0,0,0,0,0,0,0,0};
  for (int kk=0; kk<32; kk++){
    const float tv = tok[(g<<5)+kk];
    const int wo = kk*32 + (q4<<3);
    #pragma unroll
    for (int j=0;j<8;j++){
      aq[j]  = fmaf(tv, Wq[wo+j], aq[j]);
      ak2[j] = fmaf(tv, Wk[wo+j], ak2[j]);
      av[j]  = fmaf(tv, Wv[wo+j], av[j]);
    }
  }
  #pragma unroll
  for (int j=0;j<8;j++){
    qL[(g<<5)+(q4<<3)+j]=aq[j];
    kL[(g<<5)+(q4<<3)+j]=ak2[j];
    vL[(g<<5)+(q4<<3)+j]=av[j];
  }
  __syncthreads();

  const float scale = 0.17677669529663689f;
  float svv[16]; float mx = -3.0e38f;
  for (int mm=0;mm<16;mm++){
    const int m = (q4<<4)+mm;
    float s2 = 0.f;
    #pragma unroll
    for (int c=0;c<32;c++) s2 = fmaf(qL[(g<<5)+c], kL[(m<<5)+c], s2);
    s2 *= scale;
    svv[mm] = s2; mx = fmaxf(mx, s2);
  }
  mx = fmaxf(mx, __shfl_xor(mx,1));
  mx = fmaxf(mx, __shfl_xor(mx,2));
  float ssum = 0.f;
  for (int mm=0;mm<16;mm++){ svv[mm] = __expf(svv[mm]-mx); ssum += svv[mm]; }
  ssum += __shfl_xor(ssum,1); ssum += __shfl_xor(ssum,2);
  const float isum = 1.0f/ssum;
  for (int mm=0;mm<16;mm++) sc[(g<<6) + (q4<<4) + mm] = svv[mm]*isum;
  __syncthreads();

  float os[8]={0,0,0,0,0,0,0,0};
  for (int m=0;m<64;m++){
    const float a = sc[(g<<6)+m];
    const int vo = (m<<5)+(q4<<3);
    #pragma unroll
    for (int j=0;j<8;j++) os[j] = fmaf(a, vL[vo+j], os[j]);
  }
  #pragma unroll
  for (int j=0;j<8;j++) osL[(g<<5)+(q4<<3)+j] = os[j];
  __syncthreads();

  // OS2T{h,l}[b][d][h*64+g] = sum_c os[g][c] * Wout[h*32+c][d]  (split bf16)
  const int d = t;
  float wcol[32];
  #pragma unroll
  for (int c=0;c<32;c++) wcol[c] = Wout[(h*32+c)*256 + d];
  uint32* orh = (uint32*)(OS2Th + ((size_t)(b*256+d))*512 + h*64);
  uint32* orl = (uint32*)(OS2Tl + ((size_t)(b*256+d))*512 + h*64);
  #pragma unroll 4
  for (int g2=0; g2<32; g2++){
    float s0=0.f, s1=0.f;
    #pragma unroll
    for (int c=0;c<32;c++){
      s0 = fmaf(osL[((g2*2  )<<5)+c], wcol[c], s0);
      s1 = fmaf(osL[((g2*2+1)<<5)+c], wcol[c], s1);
    }
    const uint32 h0 = f2bf(s0), h1 = f2bf(s1);
    orh[g2] = h0 | (h1<<16);
    orl[g2] = f2bf(s0 - bfl(h0)) | (f2bf(s1 - bfl(h1)) << 16);
  }
}

// ---------------- k3: out = swg @ (OS2Th+OS2Tl)^T + b_out (register MFMA GEMM) ----------------
__global__ __launch_bounds__(256) void k3_kernel(
    const ushort* __restrict__ swg,
    const ushort* __restrict__ OS2Th,
    const ushort* __restrict__ OS2Tl,
    const float* __restrict__ bout,
    float* __restrict__ out)
{
  const int t = threadIdx.x, w = t>>6, l = t&63, rg = l>>4, c16 = l&15;
  const int blk = blockIdx.x;
  const long gn0 = (long)blk<<7;
  const int b = blk>>9;
  f32x4 acc[8][4];
  #pragma unroll
  for (int r=0;r<8;r++)
    #pragma unroll
    for (int c=0;c<4;c++) acc[r][c] = (f32x4){0.f,0.f,0.f,0.f};
  const ushort* swp = swg + (gn0<<9);
  const long obb = (((long)(b<<8) + (w<<6))<<9);
  for (int kb=0;kb<16;kb++){
    s16x8 aS[8];
    #pragma unroll
    for (int r=0;r<8;r++)
      aS[r] = *(const s16x8*)(swp + ((long)((r<<4)+c16)<<9) + (kb<<5)+(rg<<3));
    #pragma unroll
    for (int c=0;c<4;c++){
      const long ro = obb + ((long)((c<<4)+c16)<<9) + (kb<<5)+(rg<<3);
      const s16x8 bh = *(const s16x8*)(OS2Th + ro);
      const s16x8 bl = *(const s16x8*)(OS2Tl + ro);
      #pragma unroll
      for (int r=0;r<8;r++)
        acc[r][c] = mfma16(aS[r], bh, acc[r][c]);
      #pragma unroll
      for (int r=0;r<8;r++)
        acc[r][c] = mfma16(aS[r], bl, acc[r][c]);
    }
  }
  float bo[4];
  #pragma unroll
  for (int c=0;c<4;c++) bo[c] = bout[(w<<6)+(c<<4)+c16];
  #pragma unroll
  for (int r=0;r<8;r++)
    #pragma unroll
    for (int c=0;c<4;c++)
      #pragma unroll
      for (int rr=0;rr<4;rr++)
        out[((gn0 + (r<<4)+(rg<<2)+rr)<<8) + (w<<6)+(c<<4)+c16] = acc[r][c][rr] + bo[c];
}

extern "C" void kernel_launch(void* const* d_in, const int* in_sizes, int n_in,
                              void* d_out, int out_size, void* d_ws, size_t ws_size,
                              hipStream_t stream)
{
  const float* x     = (const float*)d_in[0];
  const float* Wfx   = (const float*)d_in[1];
  const float* bfx   = (const float*)d_in[2];
  const float* Wx    = (const float*)d_in[3];
  const float* bx    = (const float*)d_in[4];
  const float* Wsl   = (const float*)d_in[5];
  const float* bsl   = (const float*)d_in[6];
  const float* temp  = (const float*)d_in[7];
  const float* Wq    = (const float*)d_in[8];
  const float* Wk    = (const float*)d_in[9];
  const float* Wv    = (const float*)d_in[10];
  const float* Wout  = (const float*)d_in[11];
  const float* bout  = (const float*)d_in[12];
  float* out = (float*)d_out;

  char* ws = (char*)d_ws;
  // ws layout (bytes), total 152,963,072:
  ushort* WlT   = (ushort*)(ws);                   // 262144
  ushort* WfxT  = (ushort*)(ws + 262144);          // 131072
  float*  blT   = (float*) (ws + 393216);          // 2048
  ushort* swg   = (ushort*)(ws + 395264);          // 134217728
  float*  stp   = (float*) (ws + 134612992);       // 16777216
  float*  normp = (float*) (ws + 151390208);       // 524288
  ushort* OS2Th = (ushort*)(ws + 151914496);       // 524288
  ushort* OS2Tl = (ushort*)(ws + 152438784);       // 524288

  prep_kernel<<<dim3(768), dim3(256), 0, stream>>>(Wfx, Wx, Wsl, bsl, bx, temp, WlT, WfxT, blT);
  k1a_kernel<<<dim3(256), dim3(512), 0, stream>>>(x, WlT, WfxT, blT, bfx, swg, stp, normp);
  k2a_kernel<<<dim3(128), dim3(256), 0, stream>>>(stp, normp);
  k2b_kernel<<<dim3(16), dim3(256), 0, stream>>>(stp, normp, Wq, Wk, Wv, Wout, OS2Th, OS2Tl);
  k3_kernel<<<dim3(1024), dim3(256), 0, stream>>>(swg, OS2Th, OS2Tl, bout, out);
}

// Round 6
// 449.871 us; speedup vs baseline: 2.7230x; 1.0162x over previous
//
#include <hip/hip_runtime.h>

#define N_ 65536

typedef unsigned int  uint32;
typedef unsigned short ushort;
typedef float  f32x4 __attribute__((ext_vector_type(4)));
typedef short  s16x8 __attribute__((ext_vector_type(8)));
typedef uint32 u32x2 __attribute__((ext_vector_type(2)));

__device__ __forceinline__ uint32 f2bf(float f){
  union{float f; uint32 i;} v; v.f=f;
  return (v.i + 0x7fffu + ((v.i>>16)&1u)) >> 16;   // RNE
}
__device__ __forceinline__ float bfl(uint32 h){     // bf16 (low 16 bits) -> float
  union{uint32 i; float f;} v; v.i = h<<16; return v.f;
}
__device__ __forceinline__ uint32 pk2(float a, float b){
  return f2bf(a) | (f2bf(b)<<16);
}
__device__ __forceinline__ f32x4 mfma16(s16x8 a, s16x8 b, f32x4 c){
  return __builtin_amdgcn_mfma_f32_16x16x32_bf16(a,b,c,0,0,0);
}

// ---------------- prep: WlT[512][256], WfxT[256][256] (bf16, k-inner), blT[512] ----------------
__global__ __launch_bounds__(256) void prep_kernel(
    const float* __restrict__ Wfx, const float* __restrict__ Wx,
    const float* __restrict__ Wsl, const float* __restrict__ bsl,
    const float* __restrict__ bx,  const float* __restrict__ temp,
    ushort* __restrict__ WlT, ushort* __restrict__ WfxT, float* __restrict__ blT)
{
  const int blk = blockIdx.x, t = threadIdx.x;
  if (blk < 512){
    const int m = blk, h = m>>6, mp = m&63;
    const float tmp = fminf(fmaxf(temp[h],0.1f),5.0f);
    float s = 0.f;
    #pragma unroll
    for (int cc=0; cc<32; cc++) s += Wx[t*256 + h*32+cc]*Wsl[cc*64+mp];
    WlT[m*256+t] = (ushort)f2bf(s/tmp);
    if (t==0){
      float bs = bsl[mp];
      for (int cc=0; cc<32; cc++) bs += bx[h*32+cc]*Wsl[cc*64+mp];
      blT[m] = bs/tmp;
    }
  } else {
    const int c = blk-512;
    WfxT[c*256+t] = (ushort)f2bf(Wfx[t*256+c]);
  }
}

// ---------------- k1a: fused proj + softmax + slice-token partials ----------------
// 64-pt tiles, 8 per block. LDS map (128 KiB):
//   [0,32K):   X tile [64 pt][512B] swizzled; after S3 per-wave fxh overlay at w*4K
//   [32K,96K): per-wave swL at 32K+w*8K: [64 m][128B] swizzled (wave-private)
//   [96K,128K): per-wave fxl at 96K+w*4K: [32 c][128B] swizzled (wave-private)
// __launch_bounds__(512,2): 2 waves/EU min (1 block/CU is LDS-forced anyway) -> 256-VGPR budget.
__global__ __launch_bounds__(512, 2)
void k1a_kernel(
    const float* __restrict__ x,
    const ushort* __restrict__ WlT,
    const ushort* __restrict__ WfxT,
    const float* __restrict__ blT,
    const float* __restrict__ bfx,
    ushort* __restrict__ swg,       // [B*N][512] bf16 (m-inner)
    float* __restrict__ stp,        // [256][8][32][64] f32
    float* __restrict__ normp)      // [256][8][64]
{
  __shared__ __align__(16) char smem[131072];
  const int t = threadIdx.x;
  const int w = t>>6, l = t&63, rg = l>>4, c16 = l&15;
  const int blk = blockIdx.x;
  const int tile0 = ((blk&127)<<3) + ((blk>>7)<<10);

  char* fxh = smem + (w<<12);             // 4 KB per wave (X overlay, post-S3)
  char* swb = smem + 32768 + (w<<13);     // 8 KB per wave
  char* fxl = smem + 98304 + (w<<12);     // 4 KB per wave (dedicated)

  f32x4 pc[2][4];      // Phase C accumulators: [c-frag][m-frag]
  #pragma unroll
  for (int i=0;i<2;i++)
    #pragma unroll
    for (int j=0;j<4;j++) pc[i][j] = (f32x4){0.f,0.f,0.f,0.f};
  f32x4 nacc[4];
  #pragma unroll
  for (int i=0;i<4;i++) nacc[i] = (f32x4){0.f,0.f,0.f,0.f};

  f32x4 blv[4];
  #pragma unroll
  for (int m=0;m<4;m++) blv[m] = *(const f32x4*)(blT + (w<<6)+(m<<4)+(rg<<2));
  float bfv[2];
  #pragma unroll
  for (int c=0;c<2;c++) bfv[c] = bfx[(w<<5)+(c<<4)+c16];

  for (int it=0; it<8; ++it) {
    const int tile = tile0 + it;
    const long gn0 = (long)tile<<6;

    __syncthreads();   // S1: prev tile's Phase-C reads (incl. fxh overlay) done
    // ---- stage X tile [64][256] -> bf16 LDS, XOR-swizzled ----
    {
      const float4* xs = (const float4*)(x + (gn0<<8));
      #pragma unroll
      for (int p=0;p<8;p++){
        const int f = t + (p<<9);
        const int row = f>>6, q = f&63;
        const float4 v = xs[f];
        u32x2 uu; uu.x = pk2(v.x, v.y); uu.y = pk2(v.z, v.w);
        *(u32x2*)(smem + (row<<9) + ((q<<3) ^ ((row&7)<<4))) = uu;
      }
    }
    __syncthreads();   // S2: X ready

    // ---- Phase A (logits^T = WlT @ X^T), one 16-pt fragment at a time ----
    #pragma unroll
    for (int nf=0; nf<4; nf++){
      f32x4 accA[4];
      #pragma unroll
      for (int m=0;m<4;m++) accA[m] = (f32x4){0.f,0.f,0.f,0.f};
      #pragma unroll
      for (int kb=0;kb<8;kb++){
        s16x8 aW[4], bX;
        #pragma unroll
        for (int m=0;m<4;m++)
          aW[m] = *(const s16x8*)(WlT + (((w<<6)+(m<<4)+c16)<<8) + (kb<<5)+(rg<<3));
        {
          const int row = (nf<<4) | c16;
          bX = *(const s16x8*)(smem + (row<<9) + (((kb<<6)+(rg<<4)) ^ ((row&7)<<4)));
        }
        #pragma unroll
        for (int m=0;m<4;m++)
          accA[m] = mfma16(aW[m], bX, accA[m]);
      }
      // softmax over m (4 m-frags in-reg x 4 rg-groups cross-lane), per pt column
      {
        f32x4 v[4];
        float mx = -3.0e38f;
        #pragma unroll
        for (int m=0;m<4;m++){
          v[m] = accA[m] + blv[m];
          mx = fmaxf(mx, fmaxf(fmaxf(v[m].x, v[m].y), fmaxf(v[m].z, v[m].w)));
        }
        mx = fmaxf(mx, __shfl_xor(mx,16));
        mx = fmaxf(mx, __shfl_xor(mx,32));
        float s = 0.f;
        #pragma unroll
        for (int m=0;m<4;m++){
          v[m].x = __expf(v[m].x-mx); v[m].y = __expf(v[m].y-mx);
          v[m].z = __expf(v[m].z-mx); v[m].w = __expf(v[m].w-mx);
          s += v[m].x+v[m].y+v[m].z+v[m].w;
        }
        s += __shfl_xor(s,16);
        s += __shfl_xor(s,32);
        const float inv = 1.0f/s;
        const long gn = gn0 + (nf<<4) + c16;
        #pragma unroll
        for (int m=0;m<4;m++){
          f32x4 sv = v[m]*inv;
          nacc[m] += sv;
          u32x2 p; p.x = pk2(sv.x, sv.y); p.y = pk2(sv.z, sv.w);
          *(u32x2*)(swg + (gn<<9) + (w<<6)+(m<<4)+(rg<<2)) = p;
          // pair-pack transpose (regs=m) -> swL [m][pt], immediately (no persistence)
          const uint32 px = (uint32)__shfl_xor((int)p.x, 1);
          const uint32 py = (uint32)__shfl_xor((int)p.y, 1);
          const bool ev = ((c16&1)==0);
          const uint32 s0 = ev ? (uint32)p.x : py;
          const uint32 s1 = ev ? px : (uint32)p.y;
          const uint32 wA = (s0 & 0xffffu) | (s1<<16);
          const uint32 wB = (s0>>16) | (s1 & 0xffff0000u);
          const int rowA = (m<<4) + (rg<<2) + (ev?0:2);
          const int cbyt = ((nf<<4) + (c16 & ~1)) << 1;
          *(uint32*)(swb + ((rowA  )<<7) + (cbyt ^ (((rowA  )&7)<<4))) = wA;
          *(uint32*)(swb + ((rowA+1)<<7) + (cbyt ^ (((rowA+1)&7)<<4))) = wB;
        }
      }
    }

    // ---- Phase B (fx = X @ Wfx): hi kept in regs (16), lo staged to LDS directly ----
    u32x2 qkh[2][4];
    {
      f32x4 accB[4][2];
      #pragma unroll
      for (int r=0;r<4;r++)
        #pragma unroll
        for (int c=0;c<2;c++) accB[r][c] = (f32x4){0.f,0.f,0.f,0.f};
      #pragma unroll
      for (int kb=0;kb<8;kb++){
        s16x8 bW[2], aX[4];
        #pragma unroll
        for (int c=0;c<2;c++)
          bW[c] = *(const s16x8*)(WfxT + (((w<<5)+(c<<4)+c16)<<8) + (kb<<5)+(rg<<3));
        #pragma unroll
        for (int r=0;r<4;r++){
          const int row = (r<<4) | c16;
          aX[r] = *(const s16x8*)(smem + (row<<9) + (((kb<<6)+(rg<<4)) ^ ((row&7)<<4)));
        }
        #pragma unroll
        for (int r=0;r<4;r++)
          #pragma unroll
          for (int c=0;c<2;c++)
            accB[r][c] = mfma16(aX[r], bW[c], accB[r][c]);
      }
      #pragma unroll
      for (int r=0;r<4;r++)
        #pragma unroll
        for (int c=0;c<2;c++){
          const float v0 = accB[r][c].x+bfv[c], v1 = accB[r][c].y+bfv[c];
          const float v2 = accB[r][c].z+bfv[c], v3 = accB[r][c].w+bfv[c];
          const uint32 h0=f2bf(v0), h1=f2bf(v1), h2=f2bf(v2), h3=f2bf(v3);
          u32x2 ph; ph.x = h0|(h1<<16); ph.y = h2|(h3<<16);
          qkh[c][r] = ph;
          u32x2 pl;
          pl.x = f2bf(v0-bfl(h0)) | (f2bf(v1-bfl(h1))<<16);
          pl.y = f2bf(v2-bfl(h2)) | (f2bf(v3-bfl(h3))<<16);
          const int row = (c<<4) + c16;
          const int cby = ((r<<5) + (rg<<3)) ^ ((row&7)<<4);
          *(u32x2*)(fxl + (row<<7) + cby) = pl;
        }
    }
    __syncthreads();   // S3: all waves done reading X -> fxh overlay allowed

    // ---- stage fx-hi into overlay ----
    #pragma unroll
    for (int cf=0; cf<2; cf++)
      #pragma unroll
      for (int r=0; r<4; r++){
        const int row = (cf<<4) + c16;
        const int cby = ((r<<5) + (rg<<3)) ^ ((row&7)<<4);
        *(u32x2*)(fxh + (row<<7) + cby) = qkh[cf][r];
      }
    asm volatile("s_waitcnt lgkmcnt(0)" ::: "memory");
    __builtin_amdgcn_sched_barrier(0);

    // ---- Phase C: pc[c][m] += fx^T-frag @ sw-frag ----
    #pragma unroll
    for (int kb2=0; kb2<2; kb2++){
      const int pby = (kb2<<6) + (rg<<4);
      s16x8 afh[2], afl[2], bfr[4];
      #pragma unroll
      for (int cf=0; cf<2; cf++){
        const int row = (cf<<4)+c16;
        const int o = pby ^ ((row&7)<<4);
        afh[cf] = *(const s16x8*)(fxh + (row<<7) + o);
        afl[cf] = *(const s16x8*)(fxl + (row<<7) + o);
      }
      #pragma unroll
      for (int mf=0; mf<4; mf++){
        const int row = (mf<<4)+c16;
        bfr[mf] = *(const s16x8*)(swb + (row<<7) + (pby ^ ((row&7)<<4)));
      }
      #pragma unroll
      for (int cf=0; cf<2; cf++)
        #pragma unroll
        for (int mf=0; mf<4; mf++){
          pc[cf][mf] = mfma16(afh[cf], bfr[mf], pc[cf][mf]);
          pc[cf][mf] = mfma16(afl[cf], bfr[mf], pc[cf][mf]);
        }
    }
  } // tiles

  // ---- epilogue: norm reduce + stores ----
  #pragma unroll
  for (int m=0;m<4;m++){
    #pragma unroll
    for (int d=1; d<16; d<<=1){
      nacc[m].x += __shfl_xor(nacc[m].x, d);
      nacc[m].y += __shfl_xor(nacc[m].y, d);
      nacc[m].z += __shfl_xor(nacc[m].z, d);
      nacc[m].w += __shfl_xor(nacc[m].w, d);
    }
  }
  if (c16==0){
    #pragma unroll
    for (int m=0;m<4;m++)
      *(f32x4*)(normp + (((blk<<3)+w)<<6) + (m<<4) + (rg<<2)) = nacc[m];
  }
  const long sb = ((long)((blk<<3)+w))<<11;   // stp[blk][w][32 c][64 m]
  #pragma unroll
  for (int cf=0;cf<2;cf++)
    #pragma unroll
    for (int mf=0;mf<4;mf++)
      #pragma unroll
      for (int r=0;r<4;r++){
        const int cc = (cf<<4)+(rg<<2)+r;
        stp[sb + (cc<<6) + (mf<<4) + c16] = pc[cf][mf][r];
      }
}

// ---------------- k2a: hierarchical partial reduce (in-place into chunk-slot grp*16) ----------------
__global__ __launch_bounds__(256) void k2a_kernel(float* __restrict__ stp, float* __restrict__ normp)
{
  const int gid = blockIdx.x;           // 128 = 16 bh * 8 grp
  const int bh = gid>>3, grp = gid&7;
  const int b = bh>>3, h = bh&7;
  const int t = threadIdx.x;
  const int blk0 = (b<<7) + (grp<<4);
  f32x4 a0 = {0,0,0,0}, a1 = {0,0,0,0};
  for (int i=0;i<16;i++){
    const f32x4* p = (const f32x4*)(stp + ((((size_t)(blk0+i)<<3)+h)<<11) + ((size_t)t<<3));
    a0 += p[0]; a1 += p[1];
  }
  f32x4* q = (f32x4*)(stp + ((((size_t)blk0<<3)+h)<<11) + ((size_t)t<<3));
  q[0] = a0; q[1] = a1;
  if (t<8){
    f32x4 n0 = {0,0,0,0}, n1 = {0,0,0,0};
    for (int i=0;i<16;i++){
      const f32x4* p = (const f32x4*)(normp + (((blk0+i)<<3)+h)*64 + (t<<3));
      n0 += p[0]; n1 += p[1];
    }
    f32x4* qn = (f32x4*)(normp + ((blk0<<3)+h)*64 + (t<<3));
    qn[0] = n0; qn[1] = n1;
  }
}

// ---------------- k2b: final reduce + tiny attention + fold W_out -> OS2T hi/lo bf16 ----------------
__global__ __launch_bounds__(256) void k2b_kernel(
    const float* __restrict__ stp, const float* __restrict__ normp,
    const float* __restrict__ Wq, const float* __restrict__ Wk, const float* __restrict__ Wv,
    const float* __restrict__ Wout, ushort* __restrict__ OS2Th, ushort* __restrict__ OS2Tl)
{
  __shared__ float nrmL[64];
  __shared__ float tok[2048];
  __shared__ float qL[2048], kL[2048], vL[2048];
  __shared__ float sc[4096];
  __shared__ float osL[2048];
  const int bh = blockIdx.x; const int b = bh>>3, h = bh&7;
  const int t = threadIdx.x;

  if (t<64){
    float s = 0.f;
    for (int g=0; g<8; g++) s += normp[((((b<<7)+(g<<4))<<3)+h)*64 + t];
    nrmL[t] = s;
  }
  __syncthreads();
  {
    f32x4 a0 = {0,0,0,0}, a1 = {0,0,0,0};
    for (int g=0; g<8; g++){
      const f32x4* p = (const f32x4*)(stp + ((((size_t)((b<<7)+(g<<4))<<3)+h)<<11) + ((size_t)t<<3));
      a0 += p[0]; a1 += p[1];
    }
    const int c = t>>3, m0 = (t&7)<<3;
    #pragma unroll
    for (int j=0;j<4;j++) tok[(m0+j)*32 + c]   = a0[j] / (nrmL[m0+j]   + 1e-5f);
    #pragma unroll
    for (int j=0;j<4;j++) tok[(m0+4+j)*32 + c] = a1[j] / (nrmL[m0+4+j] + 1e-5f);
  }
  __syncthreads();

  const int g = t>>2, q4 = t&3;
  float aq[8]={0,0,0,0,0,0,0,0}, ak2[8]={0,0,0,0,0,0,0,0}, av[8]={0,0,0,0,0,0,0,0};
  for (int kk=0; kk<32; kk++){
    const float tv = tok[(g<<5)+kk];
    const int wo = kk*32 + (q4<<3);
    #pragma unroll
    for (int j=0;j<8;j++){
      aq[j]  = fmaf(tv, Wq[wo+j], aq[j]);
      ak2[j] = fmaf(tv, Wk[wo+j], ak2[j]);
      av[j]  = fmaf(tv, Wv[wo+j], av[j]);
    }
  }
  #pragma unroll
  for (int j=0;j<8;j++){
    qL[(g<<5)+(q4<<3)+j]=aq[j];
    kL[(g<<5)+(q4<<3)+j]=ak2[j];
    vL[(g<<5)+(q4<<3)+j]=av[j];
  }
  __syncthreads();

  const float scale = 0.17677669529663689f;
  float svv[16]; float mx = -3.0e38f;
  for (int mm=0;mm<16;mm++){
    const int m = (q4<<4)+mm;
    float s2 = 0.f;
    #pragma unroll
    for (int c=0;c<32;c++) s2 = fmaf(qL[(g<<5)+c], kL[(m<<5)+c], s2);
    s2 *= scale;
    svv[mm] = s2; mx = fmaxf(mx, s2);
  }
  mx = fmaxf(mx, __shfl_xor(mx,1));
  mx = fmaxf(mx, __shfl_xor(mx,2));
  float ssum = 0.f;
  for (int mm=0;mm<16;mm++){ svv[mm] = __expf(svv[mm]-mx); ssum += svv[mm]; }
  ssum += __shfl_xor(ssum,1); ssum += __shfl_xor(ssum,2);
  const float isum = 1.0f/ssum;
  for (int mm=0;mm<16;mm++) sc[(g<<6) + (q4<<4) + mm] = svv[mm]*isum;
  __syncthreads();

  float os[8]={0,0,0,0,0,0,0,0};
  for (int m=0;m<64;m++){
    const float a = sc[(g<<6)+m];
    const int vo = (m<<5)+(q4<<3);
    #pragma unroll
    for (int j=0;j<8;j++) os[j] = fmaf(a, vL[vo+j], os[j]);
  }
  #pragma unroll
  for (int j=0;j<8;j++) osL[(g<<5)+(q4<<3)+j] = os[j];
  __syncthreads();

  // OS2T{h,l}[b][d][h*64+g] = sum_c os[g][c] * Wout[h*32+c][d]  (split bf16)
  const int d = t;
  float wcol[32];
  #pragma unroll
  for (int c=0;c<32;c++) wcol[c] = Wout[(h*32+c)*256 + d];
  uint32* orh = (uint32*)(OS2Th + ((size_t)(b*256+d))*512 + h*64);
  uint32* orl = (uint32*)(OS2Tl + ((size_t)(b*256+d))*512 + h*64);
  #pragma unroll 4
  for (int g2=0; g2<32; g2++){
    float s0=0.f, s1=0.f;
    #pragma unroll
    for (int c=0;c<32;c++){
      s0 = fmaf(osL[((g2*2  )<<5)+c], wcol[c], s0);
      s1 = fmaf(osL[((g2*2+1)<<5)+c], wcol[c], s1);
    }
    const uint32 h0 = f2bf(s0), h1 = f2bf(s1);
    orh[g2] = h0 | (h1<<16);
    orl[g2] = f2bf(s0 - bfl(h0)) | (f2bf(s1 - bfl(h1)) << 16);
  }
}

// ---------------- k3: out = swg @ (OS2Th+OS2Tl)^T + b_out (register MFMA GEMM) ----------------
__global__ __launch_bounds__(256) void k3_kernel(
    const ushort* __restrict__ swg,
    const ushort* __restrict__ OS2Th,
    const ushort* __restrict__ OS2Tl,
    const float* __restrict__ bout,
    float* __restrict__ out)
{
  const int t = threadIdx.x, w = t>>6, l = t&63, rg = l>>4, c16 = l&15;
  const int blk = blockIdx.x;
  const long gn0 = (long)blk<<7;
  const int b = blk>>9;
  f32x4 acc[8][4];
  #pragma unroll
  for (int r=0;r<8;r++)
    #pragma unroll
    for (int c=0;c<4;c++) acc[r][c] = (f32x4){0.f,0.f,0.f,0.f};
  const ushort* swp = swg + (gn0<<9);
  const long obb = (((long)(b<<8) + (w<<6))<<9);
  for (int kb=0;kb<16;kb++){
    s16x8 aS[8];
    #pragma unroll
    for (int r=0;r<8;r++)
      aS[r] = *(const s16x8*)(swp + ((long)((r<<4)+c16)<<9) + (kb<<5)+(rg<<3));
    #pragma unroll
    for (int c=0;c<4;c++){
      const long ro = obb + ((long)((c<<4)+c16)<<9) + (kb<<5)+(rg<<3);
      const s16x8 bh = *(const s16x8*)(OS2Th + ro);
      const s16x8 bl = *(const s16x8*)(OS2Tl + ro);
      #pragma unroll
      for (int r=0;r<8;r++)
        acc[r][c] = mfma16(aS[r], bh, acc[r][c]);
      #pragma unroll
      for (int r=0;r<8;r++)
        acc[r][c] = mfma16(aS[r], bl, acc[r][c]);
    }
  }
  float bo[4];
  #pragma unroll
  for (int c=0;c<4;c++) bo[c] = bout[(w<<6)+(c<<4)+c16];
  #pragma unroll
  for (int r=0;r<8;r++)
    #pragma unroll
    for (int c=0;c<4;c++)
      #pragma unroll
      for (int rr=0;rr<4;rr++)
        out[((gn0 + (r<<4)+(rg<<2)+rr)<<8) + (w<<6)+(c<<4)+c16] = acc[r][c][rr] + bo[c];
}

extern "C" void kernel_launch(void* const* d_in, const int* in_sizes, int n_in,
                              void* d_out, int out_size, void* d_ws, size_t ws_size,
                              hipStream_t stream)
{
  const float* x     = (const float*)d_in[0];
  const float* Wfx   = (const float*)d_in[1];
  const float* bfx   = (const float*)d_in[2];
  const float* Wx    = (const float*)d_in[3];
  const float* bx    = (const float*)d_in[4];
  const float* Wsl   = (const float*)d_in[5];
  const float* bsl   = (const float*)d_in[6];
  const float* temp  = (const float*)d_in[7];
  const float* Wq    = (const float*)d_in[8];
  const float* Wk    = (const float*)d_in[9];
  const float* Wv    = (const float*)d_in[10];
  const float* Wout  = (const float*)d_in[11];
  const float* bout  = (const float*)d_in[12];
  float* out = (float*)d_out;

  char* ws = (char*)d_ws;
  // ws layout (bytes), total 152,963,072:
  ushort* WlT   = (ushort*)(ws);                   // 262144
  ushort* WfxT  = (ushort*)(ws + 262144);          // 131072
  float*  blT   = (float*) (ws + 393216);          // 2048
  ushort* swg   = (ushort*)(ws + 395264);          // 134217728
  float*  stp   = (float*) (ws + 134612992);       // 16777216
  float*  normp = (float*) (ws + 151390208);       // 524288
  ushort* OS2Th = (ushort*)(ws + 151914496);       // 524288
  ushort* OS2Tl = (ushort*)(ws + 152438784);       // 524288

  prep_kernel<<<dim3(768), dim3(256), 0, stream>>>(Wfx, Wx, Wsl, bsl, bx, temp, WlT, WfxT, blT);
  k1a_kernel<<<dim3(256), dim3(512), 0, stream>>>(x, WlT, WfxT, blT, bfx, swg, stp, normp);
  k2a_kernel<<<dim3(128), dim3(256), 0, stream>>>(stp, normp);
  k2b_kernel<<<dim3(16), dim3(256), 0, stream>>>(stp, normp, Wq, Wk, Wv, Wout, OS2Th, OS2Tl);
  k3_kernel<<<dim3(1024), dim3(256), 0, stream>>>(swg, OS2Th, OS2Tl, bout, out);
}